// Round 1
// baseline (6496.914 us; speedup 1.0000x reference)
//
#include <hip/hip_runtime.h>
#include <hip/hip_bf16.h>

// Problem constants (AGIFORMERBlock): B=2, S=2048, D=1024, H=16, F=4096, E=8, K=2
constexpr int Bc = 2;
constexpr int Sc = 2048;
constexpr int Dc = 1024;
constexpr int Hc = 16;
constexpr int DHc = 64;
constexpr int Fc = 4096;
constexpr int Ec = 8;
constexpr int NTOK = Bc * Sc;  // 4096 tokens

// ---------------------------------------------------------------------------
// LayerNorm: one block per row (D=1024), 256 threads
// ---------------------------------------------------------------------------
__global__ __launch_bounds__(256) void ln_kernel(const float* __restrict__ x,
                                                 const float* __restrict__ g,
                                                 const float* __restrict__ b,
                                                 float* __restrict__ h) {
    int row = blockIdx.x;
    int tid = threadIdx.x;
    const float* xr = x + (size_t)row * Dc;
    float s = 0.f, ss = 0.f;
    for (int i = tid; i < Dc; i += 256) {
        float v = xr[i];
        s += v;
        ss += v * v;
    }
    __shared__ float r1[256], r2[256];
    r1[tid] = s; r2[tid] = ss;
    __syncthreads();
    for (int off = 128; off > 0; off >>= 1) {
        if (tid < off) { r1[tid] += r1[tid + off]; r2[tid] += r2[tid + off]; }
        __syncthreads();
    }
    float mean = r1[0] * (1.0f / Dc);
    float var = r2[0] * (1.0f / Dc) - mean * mean;
    float rs = rsqrtf(var + 1e-5f);
    float* hr = h + (size_t)row * Dc;
    for (int i = tid; i < Dc; i += 256) {
        hr[i] = (xr[i] - mean) * rs * g[i] + b[i];
    }
}

// ---------------------------------------------------------------------------
// Generic fp32 tiled GEMM: C[M,N] = A[M,K] @ W[K,N]  (+ optional residual)
// 64x64 tile, BK=16, 256 threads, each thread 4x4 outputs.
// ---------------------------------------------------------------------------
template <bool RES>
__global__ __launch_bounds__(256) void gemm_kernel(const float* __restrict__ A,
                                                   const float* __restrict__ W,
                                                   const float* __restrict__ res,
                                                   float* __restrict__ C,
                                                   int M, int N, int Kd) {
    __shared__ float As[16][68];  // [k][m] (transposed A tile)
    __shared__ float Bs[16][68];  // [k][n]
    int tid = threadIdx.x;
    int m0 = blockIdx.y * 64, n0 = blockIdx.x * 64;
    int tx = tid & 15, ty = tid >> 4;
    int la_r = tid >> 2, la_s = (tid & 3) * 4;   // A: row la_r, cols la_s..+3
    int lb_r = tid >> 4, lb_s = (tid & 15) * 4;  // W: row lb_r, cols lb_s..+3
    float acc[4][4] = {};
    for (int k0 = 0; k0 < Kd; k0 += 16) {
        float4 av = *(const float4*)(A + (size_t)(m0 + la_r) * Kd + k0 + la_s);
        float4 bv = *(const float4*)(W + (size_t)(k0 + lb_r) * N + n0 + lb_s);
        __syncthreads();
        As[la_s + 0][la_r] = av.x;
        As[la_s + 1][la_r] = av.y;
        As[la_s + 2][la_r] = av.z;
        As[la_s + 3][la_r] = av.w;
        *(float4*)&Bs[lb_r][lb_s] = bv;
        __syncthreads();
#pragma unroll
        for (int kk = 0; kk < 16; kk++) {
            float4 a = *(const float4*)&As[kk][ty * 4];
            float4 b = *(const float4*)&Bs[kk][tx * 4];
            acc[0][0] += a.x * b.x; acc[0][1] += a.x * b.y; acc[0][2] += a.x * b.z; acc[0][3] += a.x * b.w;
            acc[1][0] += a.y * b.x; acc[1][1] += a.y * b.y; acc[1][2] += a.y * b.z; acc[1][3] += a.y * b.w;
            acc[2][0] += a.z * b.x; acc[2][1] += a.z * b.y; acc[2][2] += a.z * b.z; acc[2][3] += a.z * b.w;
            acc[3][0] += a.w * b.x; acc[3][1] += a.w * b.y; acc[3][2] += a.w * b.z; acc[3][3] += a.w * b.w;
        }
    }
#pragma unroll
    for (int i = 0; i < 4; i++) {
#pragma unroll
        for (int j = 0; j < 4; j++) {
            size_t idx = (size_t)(m0 + ty * 4 + i) * N + n0 + tx * 4 + j;
            float v = acc[i][j];
            if (RES) v += res[idx];
            C[idx] = v;
        }
    }
}

// ---------------------------------------------------------------------------
// Flash-style attention. Grid (S/64, H, B), 256 threads.
// Q-tile 64 rows; K/V tiles of 32; online softmax.
// ---------------------------------------------------------------------------
__global__ __launch_bounds__(256) void attn_kernel(const float* __restrict__ Q,
                                                   const float* __restrict__ Kt,
                                                   const float* __restrict__ V,
                                                   float* __restrict__ O) {
    __shared__ float qs[64][65];
    __shared__ float ks[32][65];
    __shared__ float vs[32][65];
    __shared__ float ssc[64][33];
    __shared__ float m_s[64], l_s[64], al_s[64];

    int q0 = blockIdx.x * 64;
    int hh = blockIdx.y;
    int bb = blockIdx.z;
    int tid = threadIdx.x;
    const size_t bofs = (size_t)bb * Sc * Dc;
    const int hc = hh * DHc;

    for (int i = tid; i < 64 * 64; i += 256) {
        int r = i >> 6, c = i & 63;
        qs[r][c] = Q[bofs + (size_t)(q0 + r) * Dc + hc + c];
    }
    if (tid < 64) { m_s[tid] = -1e30f; l_s[tid] = 0.f; }
    float acc[16];
#pragma unroll
    for (int j = 0; j < 16; j++) acc[j] = 0.f;
    int d = tid & 63, qr = tid >> 6;  // this thread owns (q = qr + 4*j, d)

    for (int kt = 0; kt < Sc / 32; kt++) {
        int k0 = kt * 32;
        __syncthreads();  // protect ks/vs/ssc from previous iteration's readers
        for (int i = tid; i < 32 * 64; i += 256) {
            int r = i >> 6, c = i & 63;
            ks[r][c] = Kt[bofs + (size_t)(k0 + r) * Dc + hc + c];
            vs[r][c] = V[bofs + (size_t)(k0 + r) * Dc + hc + c];
        }
        __syncthreads();
        // scores: 64 q x 32 k
        for (int i = tid; i < 64 * 32; i += 256) {
            int qi = i >> 5, ki = i & 31;
            float sum = 0.f;
#pragma unroll
            for (int dd = 0; dd < 64; dd++) sum += qs[qi][dd] * ks[ki][dd];
            ssc[qi][ki] = sum * 0.125f;  // 1/sqrt(64)
        }
        __syncthreads();
        // online softmax per q-row (threads 0..63)
        if (tid < 64) {
            float mo = m_s[tid];
            float rm = -1e30f;
            for (int kx = 0; kx < 32; kx++) rm = fmaxf(rm, ssc[tid][kx]);
            float mn = fmaxf(mo, rm);
            float al = __expf(mo - mn);
            float psum = 0.f;
            for (int kx = 0; kx < 32; kx++) {
                float p = __expf(ssc[tid][kx] - mn);
                ssc[tid][kx] = p;
                psum += p;
            }
            l_s[tid] = l_s[tid] * al + psum;
            m_s[tid] = mn;
            al_s[tid] = al;
        }
        __syncthreads();
        // O update
#pragma unroll
        for (int j = 0; j < 16; j++) {
            int qi = qr + 4 * j;
            float a = acc[j] * al_s[qi];
#pragma unroll
            for (int kx = 0; kx < 32; kx++) a += ssc[qi][kx] * vs[kx][d];
            acc[j] = a;
        }
    }
#pragma unroll
    for (int j = 0; j < 16; j++) {
        int qi = qr + 4 * j;
        O[bofs + (size_t)(q0 + qi) * Dc + hc + d] = acc[j] / l_s[qi];
    }
}

// ---------------------------------------------------------------------------
// Router: logits = x2 @ Wg [D x 8], softmax, top-2, renormalize.
// One block per token.
// ---------------------------------------------------------------------------
__global__ __launch_bounds__(256) void router_kernel(const float* __restrict__ x2,
                                                     const float* __restrict__ Wg,
                                                     int* __restrict__ topi,
                                                     float* __restrict__ topw,
                                                     int* __restrict__ counts) {
    int t = blockIdx.x, tid = threadIdx.x;
    float p[Ec] = {};
    const float* xr = x2 + (size_t)t * Dc;
    for (int k = tid; k < Dc; k += 256) {
        float xv = xr[k];
        const float* wr = Wg + (size_t)k * Ec;
#pragma unroll
        for (int e = 0; e < Ec; e++) p[e] += xv * wr[e];
    }
    __shared__ float red[256 * Ec];
#pragma unroll
    for (int e = 0; e < Ec; e++) red[tid * Ec + e] = p[e];
    __syncthreads();
    for (int off = 128; off > 0; off >>= 1) {
        if (tid < off) {
#pragma unroll
            for (int e = 0; e < Ec; e++) red[tid * Ec + e] += red[(tid + off) * Ec + e];
        }
        __syncthreads();
    }
    if (tid == 0) {
        float l[Ec];
        float mx = -1e30f;
#pragma unroll
        for (int e = 0; e < Ec; e++) { l[e] = red[e]; mx = fmaxf(mx, l[e]); }
#pragma unroll
        for (int e = 0; e < Ec; e++) l[e] = __expf(l[e] - mx);
        int i0 = 0;
#pragma unroll
        for (int e = 1; e < Ec; e++) if (l[e] > l[i0]) i0 = e;
        int i1 = (i0 == 0) ? 1 : 0;
#pragma unroll
        for (int e = 0; e < Ec; e++) if (e != i0 && l[e] > l[i1]) i1 = e;
        float v0 = l[i0], v1 = l[i1];
        float inv = 1.0f / (v0 + v1);
        topi[t * 2 + 0] = i0;
        topi[t * 2 + 1] = i1;
        topw[t * 2 + 0] = v0 * inv;
        topw[t * 2 + 1] = v1 * inv;
        atomicAdd(&counts[i0], 1);
        atomicAdd(&counts[i1], 1);
    }
}

__global__ void zero_small(int* counts, int* cursor) {
    int i = threadIdx.x;
    if (i < Ec) { counts[i] = 0; cursor[i] = 0; }
}

__global__ void scan_kernel(const int* counts, int* offsets) {
    if (threadIdx.x == 0) {
        int s = 0;
        for (int e = 0; e < Ec; e++) { offsets[e] = s; s += counts[e]; }
    }
}

__global__ __launch_bounds__(256) void scatter_kernel(const int* __restrict__ topi,
                                                      const float* __restrict__ topw,
                                                      const int* __restrict__ offsets,
                                                      int* __restrict__ cursor,
                                                      int* __restrict__ list_tok,
                                                      float* __restrict__ list_w) {
    int t = blockIdx.x * 256 + threadIdx.x;
    if (t >= NTOK) return;
    for (int s2 = 0; s2 < 2; s2++) {
        int e = topi[t * 2 + s2];
        int pos = atomicAdd(&cursor[e], 1);
        int p = offsets[e] + pos;
        list_tok[p] = t;
        list_w[p] = topw[t * 2 + s2];
    }
}

__device__ __forceinline__ float gelu_tanh(float x) {
    float x3 = x * x * x;
    float t = tanhf(0.79788456080286535588f * (x + 0.044715f * x3));
    return 0.5f * x * (1.0f + t);
}

// ---------------------------------------------------------------------------
// MoE GEMM1: for expert e, gathered rows of x2 @ W1[e] + b1[e] -> gelu -> h1 (bf16)
// Grid (F/64, 64, E). Tiles past the expert's count exit early.
// ---------------------------------------------------------------------------
__global__ __launch_bounds__(256) void moe_gemm1(const float* __restrict__ x2,
                                                 const float* __restrict__ W1,
                                                 const float* __restrict__ b1,
                                                 const int* __restrict__ counts,
                                                 const int* __restrict__ offsets,
                                                 const int* __restrict__ list_tok,
                                                 __hip_bfloat16* __restrict__ h1) {
    int e = blockIdx.z;
    int cnt = counts[e];
    int r0 = blockIdx.y * 64;
    if (r0 >= cnt) return;
    int off = offsets[e];
    int f0 = blockIdx.x * 64;
    __shared__ float As[16][68];
    __shared__ float Bs[16][68];
    __shared__ int toks[64];
    int tid = threadIdx.x;
    if (tid < 64) {
        int r = min(r0 + tid, cnt - 1);
        toks[tid] = list_tok[off + r];
    }
    __syncthreads();
    int tx = tid & 15, ty = tid >> 4;
    int la_r = tid >> 2, la_s = (tid & 3) * 4;
    int lb_r = tid >> 4, lb_s = (tid & 15) * 4;
    const float* Wb = W1 + (size_t)e * Dc * Fc;
    const float* Arow = x2 + (size_t)toks[la_r] * Dc;
    float acc[4][4] = {};
    for (int k0 = 0; k0 < Dc; k0 += 16) {
        float4 av = *(const float4*)(Arow + k0 + la_s);
        float4 bv = *(const float4*)(Wb + (size_t)(k0 + lb_r) * Fc + f0 + lb_s);
        __syncthreads();
        As[la_s + 0][la_r] = av.x;
        As[la_s + 1][la_r] = av.y;
        As[la_s + 2][la_r] = av.z;
        As[la_s + 3][la_r] = av.w;
        *(float4*)&Bs[lb_r][lb_s] = bv;
        __syncthreads();
#pragma unroll
        for (int kk = 0; kk < 16; kk++) {
            float4 a = *(const float4*)&As[kk][ty * 4];
            float4 b = *(const float4*)&Bs[kk][tx * 4];
            acc[0][0] += a.x * b.x; acc[0][1] += a.x * b.y; acc[0][2] += a.x * b.z; acc[0][3] += a.x * b.w;
            acc[1][0] += a.y * b.x; acc[1][1] += a.y * b.y; acc[1][2] += a.y * b.z; acc[1][3] += a.y * b.w;
            acc[2][0] += a.z * b.x; acc[2][1] += a.z * b.y; acc[2][2] += a.z * b.z; acc[2][3] += a.z * b.w;
            acc[3][0] += a.w * b.x; acc[3][1] += a.w * b.y; acc[3][2] += a.w * b.z; acc[3][3] += a.w * b.w;
        }
    }
    const float* b1e = b1 + (size_t)e * Fc;
#pragma unroll
    for (int i = 0; i < 4; i++) {
        int r = ty * 4 + i;
        if (r0 + r < cnt) {
            size_t p = (size_t)(off + r0 + r);
#pragma unroll
            for (int j = 0; j < 4; j++) {
                int f = f0 + tx * 4 + j;
                float v = acc[i][j] + b1e[f];
                h1[p * Fc + f] = __float2bfloat16(gelu_tanh(v));
            }
        }
    }
}

// ---------------------------------------------------------------------------
// MoE GEMM2: h1 (bf16, grouped rows) @ W2[e] + b2[e]; weighted atomicAdd into out.
// Grid (D/64, 64, E).
// ---------------------------------------------------------------------------
__global__ __launch_bounds__(256) void moe_gemm2(const __hip_bfloat16* __restrict__ h1,
                                                 const float* __restrict__ W2,
                                                 const float* __restrict__ b2,
                                                 const int* __restrict__ counts,
                                                 const int* __restrict__ offsets,
                                                 const int* __restrict__ list_tok,
                                                 const float* __restrict__ list_w,
                                                 float* __restrict__ out) {
    int e = blockIdx.z;
    int cnt = counts[e];
    int r0 = blockIdx.y * 64;
    if (r0 >= cnt) return;
    int off = offsets[e];
    int n0 = blockIdx.x * 64;
    __shared__ float As[16][68];
    __shared__ float Bs[16][68];
    __shared__ int toks[64];
    __shared__ float wts[64];
    int tid = threadIdx.x;
    if (tid < 64) {
        int r = min(r0 + tid, cnt - 1);
        toks[tid] = list_tok[off + r];
        wts[tid] = list_w[off + r];
    }
    __syncthreads();
    int tx = tid & 15, ty = tid >> 4;
    int la_r = tid >> 2, la_s = (tid & 3) * 4;
    int lb_r = tid >> 4, lb_s = (tid & 15) * 4;
    const float* Wb = W2 + (size_t)e * Fc * Dc;
    const __hip_bfloat16* Arow = h1 + (size_t)(off + min(r0 + la_r, cnt - 1)) * Fc;
    float acc[4][4] = {};
    for (int k0 = 0; k0 < Fc; k0 += 16) {
        uint2 u = *(const uint2*)(Arow + k0 + la_s);
        float4 bv = *(const float4*)(Wb + (size_t)(k0 + lb_r) * Dc + n0 + lb_s);
        float a0 = __uint_as_float(u.x << 16);
        float a1 = __uint_as_float(u.x & 0xffff0000u);
        float a2 = __uint_as_float(u.y << 16);
        float a3 = __uint_as_float(u.y & 0xffff0000u);
        __syncthreads();
        As[la_s + 0][la_r] = a0;
        As[la_s + 1][la_r] = a1;
        As[la_s + 2][la_r] = a2;
        As[la_s + 3][la_r] = a3;
        *(float4*)&Bs[lb_r][lb_s] = bv;
        __syncthreads();
#pragma unroll
        for (int kk = 0; kk < 16; kk++) {
            float4 a = *(const float4*)&As[kk][ty * 4];
            float4 b = *(const float4*)&Bs[kk][tx * 4];
            acc[0][0] += a.x * b.x; acc[0][1] += a.x * b.y; acc[0][2] += a.x * b.z; acc[0][3] += a.x * b.w;
            acc[1][0] += a.y * b.x; acc[1][1] += a.y * b.y; acc[1][2] += a.y * b.z; acc[1][3] += a.y * b.w;
            acc[2][0] += a.z * b.x; acc[2][1] += a.z * b.y; acc[2][2] += a.z * b.z; acc[2][3] += a.z * b.w;
            acc[3][0] += a.w * b.x; acc[3][1] += a.w * b.y; acc[3][2] += a.w * b.z; acc[3][3] += a.w * b.w;
        }
    }
    const float* b2e = b2 + (size_t)e * Dc;
#pragma unroll
    for (int i = 0; i < 4; i++) {
        int r = ty * 4 + i;
        if (r0 + r < cnt) {
            int tok = toks[r];
            float w = wts[r];
#pragma unroll
            for (int j = 0; j < 4; j++) {
                int dcol = n0 + tx * 4 + j;
                float v = acc[i][j] + b2e[dcol];
                atomicAdd(&out[(size_t)tok * Dc + dcol], w * v);
            }
        }
    }
}

__global__ __launch_bounds__(256) void copy_kernel(const float* __restrict__ src,
                                                   float* __restrict__ dst, int n4) {
    int i = blockIdx.x * 256 + threadIdx.x;
    if (i < n4) ((float4*)dst)[i] = ((const float4*)src)[i];
}

// ---------------------------------------------------------------------------
// Launch. Workspace layout (needs ~96.5 MB):
//   [0,16M)   h      (later aliased by h1)
//   [16,32M)  q      (aliased by h1)
//   [32,48M)  k      (aliased by h1)
//   [48,64M)  v      (aliased by h1)
//   [64,80M)  attn_o
//   [80,96M)  x2
//   h1 (bf16, 8192 x 4096 = 64M) at [0,64M)  -- h/q/k/v dead by MoE phase
//   [96M+..)  router/top-k/list scratch
// ---------------------------------------------------------------------------
extern "C" void kernel_launch(void* const* d_in, const int* in_sizes, int n_in,
                              void* d_out, int out_size, void* d_ws, size_t ws_size,
                              hipStream_t stream) {
    const float* x    = (const float*)d_in[0];
    const float* ln_g = (const float*)d_in[1];
    const float* ln_b = (const float*)d_in[2];
    const float* Wq   = (const float*)d_in[3];
    const float* Wk   = (const float*)d_in[4];
    const float* Wv   = (const float*)d_in[5];
    const float* Wo   = (const float*)d_in[6];
    const float* Wg   = (const float*)d_in[7];
    const float* W1   = (const float*)d_in[8];
    const float* b1   = (const float*)d_in[9];
    const float* W2   = (const float*)d_in[10];
    const float* b2   = (const float*)d_in[11];
    float* out = (float*)d_out;

    char* ws = (char*)d_ws;
    const size_t MB = 1ull << 20;
    float* h  = (float*)(ws + 0 * MB);
    float* q  = (float*)(ws + 16 * MB);
    float* k  = (float*)(ws + 32 * MB);
    float* v  = (float*)(ws + 48 * MB);
    float* ao = (float*)(ws + 64 * MB);
    float* x2 = (float*)(ws + 80 * MB);
    __hip_bfloat16* h1 = (__hip_bfloat16*)(ws + 0 * MB);
    float* topw    = (float*)(ws + 96 * MB);
    int*   topi    = (int*)(ws + 96 * MB + 32 * 1024);
    int*   counts  = (int*)(ws + 96 * MB + 64 * 1024);
    int*   offsets = (int*)(ws + 96 * MB + 64 * 1024 + 256);
    int*   cursor  = (int*)(ws + 96 * MB + 64 * 1024 + 512);
    int*   list_tok = (int*)(ws + 96 * MB + 128 * 1024);
    float* list_w   = (float*)(ws + 96 * MB + 192 * 1024);

    // --- attention ---
    ln_kernel<<<NTOK, 256, 0, stream>>>(x, ln_g, ln_b, h);
    gemm_kernel<false><<<dim3(Dc / 64, NTOK / 64), 256, 0, stream>>>(h, Wq, nullptr, q, NTOK, Dc, Dc);
    gemm_kernel<false><<<dim3(Dc / 64, NTOK / 64), 256, 0, stream>>>(h, Wk, nullptr, k, NTOK, Dc, Dc);
    gemm_kernel<false><<<dim3(Dc / 64, NTOK / 64), 256, 0, stream>>>(h, Wv, nullptr, v, NTOK, Dc, Dc);
    attn_kernel<<<dim3(Sc / 64, Hc, Bc), 256, 0, stream>>>(q, k, v, ao);
    gemm_kernel<true><<<dim3(Dc / 64, NTOK / 64), 256, 0, stream>>>(ao, Wo, x, x2, NTOK, Dc, Dc);

    // --- MoE routing ---
    zero_small<<<1, 64, 0, stream>>>(counts, cursor);
    router_kernel<<<NTOK, 256, 0, stream>>>(x2, Wg, topi, topw, counts);
    scan_kernel<<<1, 1, 0, stream>>>(counts, offsets);
    scatter_kernel<<<NTOK / 256, 256, 0, stream>>>(topi, topw, offsets, cursor, list_tok, list_w);

    // --- MoE experts (grouped) ---
    moe_gemm1<<<dim3(Fc / 64, NTOK / 64, Ec), 256, 0, stream>>>(x2, W1, b1, counts, offsets, list_tok, h1);
    copy_kernel<<<(NTOK * Dc / 4) / 256, 256, 0, stream>>>(x2, out, NTOK * Dc / 4);
    moe_gemm2<<<dim3(Dc / 64, NTOK / 64, Ec), 256, 0, stream>>>(h1, W2, b2, counts, offsets, list_tok, list_w, out);
}

// Round 2
// 1663.493 us; speedup vs baseline: 3.9056x; 3.9056x over previous
//
#include <hip/hip_runtime.h>
#include <hip/hip_bf16.h>

// AGIFORMERBlock: B=2, S=2048, D=1024, H=16 (dh=64), F=4096, E=8, K=2
constexpr int Sc = 2048;
constexpr int Dc = 1024;
constexpr int Fc = 4096;
constexpr int Ec = 8;
constexpr int NTOK = 4096;  // B*S

typedef __attribute__((ext_vector_type(8))) short short8;
typedef __attribute__((ext_vector_type(4))) float floatx4;
typedef unsigned short u16;

__device__ __forceinline__ u16 f2bf(float f) {
    __hip_bfloat16 h = __float2bfloat16(f);
    return *reinterpret_cast<u16*>(&h);
}

__device__ __forceinline__ float gelu_tanh(float x) {
    float x3 = x * x * x;
    float t = tanhf(0.79788456080286535588f * (x + 0.044715f * x3));
    return 0.5f * x * (1.0f + t);
}

// ---------------------------------------------------------------------------
// Transpose-cast: src fp32 [R][C] -> dst bf16 [C][R].  Grid (C/64, R/64, Z).
// ---------------------------------------------------------------------------
__global__ __launch_bounds__(256) void tcast_kernel(const float* __restrict__ src,
                                                    u16* __restrict__ dst,
                                                    int R, int C,
                                                    size_t sstride, size_t dstride) {
    __shared__ float t[64][65];
    const float* s = src + (size_t)blockIdx.z * sstride;
    u16* d = dst + (size_t)blockIdx.z * dstride;
    int r0 = blockIdx.y * 64, c0 = blockIdx.x * 64;
    int tid = threadIdx.x;
#pragma unroll
    for (int i = 0; i < 4; i++) {
        int c = tid + i * 256;
        int row = c >> 4, col4 = (c & 15) * 4;
        float4 v = *(const float4*)(s + (size_t)(r0 + row) * C + c0 + col4);
        t[row][col4 + 0] = v.x;
        t[row][col4 + 1] = v.y;
        t[row][col4 + 2] = v.z;
        t[row][col4 + 3] = v.w;
    }
    __syncthreads();
#pragma unroll
    for (int i = 0; i < 2; i++) {
        int c = tid + i * 256;
        int dr = c >> 3, m8 = (c & 7) * 8;
        union { u16 us[8]; uint4 v; } pk;
#pragma unroll
        for (int j = 0; j < 8; j++) pk.us[j] = f2bf(t[m8 + j][dr]);
        *(uint4*)(d + (size_t)(c0 + dr) * R + r0 + m8) = pk.v;
    }
}

// ---------------------------------------------------------------------------
// LayerNorm -> bf16. One block per row, 256 threads, D=1024 (one float4/thread)
// ---------------------------------------------------------------------------
__global__ __launch_bounds__(256) void ln_kernel(const float* __restrict__ x,
                                                 const float* __restrict__ g,
                                                 const float* __restrict__ b,
                                                 u16* __restrict__ hb) {
    int row = blockIdx.x, tid = threadIdx.x;
    const float* xr = x + (size_t)row * Dc;
    float4 xv = ((const float4*)xr)[tid];
    float s = xv.x + xv.y + xv.z + xv.w;
    float ss = xv.x * xv.x + xv.y * xv.y + xv.z * xv.z + xv.w * xv.w;
    __shared__ float r1[256], r2[256];
    r1[tid] = s; r2[tid] = ss;
    __syncthreads();
    for (int off = 128; off > 0; off >>= 1) {
        if (tid < off) { r1[tid] += r1[tid + off]; r2[tid] += r2[tid + off]; }
        __syncthreads();
    }
    float mean = r1[0] * (1.0f / Dc);
    float var = r2[0] * (1.0f / Dc) - mean * mean;
    float rs = rsqrtf(var + 1e-5f);
    float4 gv = ((const float4*)g)[tid];
    float4 bv = ((const float4*)b)[tid];
    ushort4 o;
    o.x = f2bf((xv.x - mean) * rs * gv.x + bv.x);
    o.y = f2bf((xv.y - mean) * rs * gv.y + bv.y);
    o.z = f2bf((xv.z - mean) * rs * gv.z + bv.z);
    o.w = f2bf((xv.w - mean) * rs * gv.w + bv.w);
    *(ushort4*)(hb + (size_t)row * Dc + tid * 4) = o;
}

// ---------------------------------------------------------------------------
// bf16 MFMA GEMM: C[M,N] = A[M,K] @ B[K,N], B given TRANSPOSED as BT[N][K].
// 128x128 tile, BK=32, 256 threads = 4 waves (2x2), each wave 64x64 (4x4 frags).
// MODE 0: QKV fused  (N=3072; cols 0-1023 -> qb, 1024-2047 -> kb, 2048.. -> vt transposed)
// MODE 1: O-proj + residual -> x2 (fp32) and x2b (bf16)
// MODE 2: MoE GEMM1 (gathered A rows via list_tok; gelu(acc+b1) -> h1 bf16)
// MODE 3: MoE GEMM2 (A = h1 slot rows; acc + b2 -> h2 fp32)
// ---------------------------------------------------------------------------
template <int MODE>
__global__ __launch_bounds__(256) void gemm_mfma(
    const u16* __restrict__ A, const u16* __restrict__ BT,
    int M, int N, int K,
    u16* __restrict__ out_q, u16* __restrict__ out_k, u16* __restrict__ out_vt,
    const float* __restrict__ resid, float* __restrict__ out_f32,
    u16* __restrict__ out_bf, const float* __restrict__ bias,
    const int* __restrict__ counts, const int* __restrict__ offsets,
    const int* __restrict__ list_tok) {
    int e = 0, cnt = 0, off = 0;
    if (MODE >= 2) {
        e = blockIdx.z;
        cnt = counts[e];
        if ((int)blockIdx.y * 128 >= cnt) return;
        off = offsets[e];
    }
    const int tid = threadIdx.x;
    const int m0 = blockIdx.y * 128, n0 = blockIdx.x * 128;
    __shared__ u16 As[128][40];
    __shared__ u16 Bs[128][40];
    __shared__ int toks[128];
    if (MODE == 2) {
        if (tid < 128) toks[tid] = list_tok[off + min(m0 + tid, cnt - 1)];
        __syncthreads();
    }
    const u16* Bbase = BT + (MODE >= 2 ? (size_t)e * N * K : 0);
    const int w = tid >> 6, lane = tid & 63;
    const int wm = (w >> 1) * 64, wn = (w & 1) * 64;
    const int lr = lane & 15, lq = lane >> 4;
    floatx4 acc[4][4];
#pragma unroll
    for (int i = 0; i < 4; i++)
#pragma unroll
        for (int j = 0; j < 4; j++) acc[i][j] = (floatx4){0.f, 0.f, 0.f, 0.f};

    for (int k0 = 0; k0 < K; k0 += 32) {
        uint4 aval[2], bval[2];
#pragma unroll
        for (int i = 0; i < 2; i++) {
            int c = tid + i * 256;
            int arow = c >> 2, k8 = (c & 3) * 8;
            size_t asrc;
            if (MODE == 2)      asrc = (size_t)toks[arow] * K + k0 + k8;
            else if (MODE == 3) asrc = (size_t)(off + min(m0 + arow, cnt - 1)) * K + k0 + k8;
            else                asrc = (size_t)(m0 + arow) * K + k0 + k8;
            aval[i] = *(const uint4*)(A + asrc);
            bval[i] = *(const uint4*)(Bbase + (size_t)(n0 + arow) * K + k0 + k8);
        }
        __syncthreads();
#pragma unroll
        for (int i = 0; i < 2; i++) {
            int c = tid + i * 256;
            int arow = c >> 2, k8 = (c & 3) * 8;
            *(uint4*)&As[arow][k8] = aval[i];
            *(uint4*)&Bs[arow][k8] = bval[i];
        }
        __syncthreads();
        short8 af[4], bf[4];
#pragma unroll
        for (int i = 0; i < 4; i++) af[i] = *(const short8*)&As[wm + i * 16 + lr][lq * 8];
#pragma unroll
        for (int j = 0; j < 4; j++) bf[j] = *(const short8*)&Bs[wn + j * 16 + lr][lq * 8];
#pragma unroll
        for (int i = 0; i < 4; i++)
#pragma unroll
            for (int j = 0; j < 4; j++)
                acc[i][j] = __builtin_amdgcn_mfma_f32_16x16x32_bf16(af[i], bf[j], acc[i][j], 0, 0, 0);
    }

    // Epilogue. C/D layout: col = lane&15, row = (lane>>4)*4 + reg.
    if (MODE == 0) {
        int mat = n0 >> 10;  // uniform per block
#pragma unroll
        for (int i = 0; i < 4; i++)
#pragma unroll
            for (int j = 0; j < 4; j++) {
                int col = n0 + wn + j * 16 + lr;
                int cc = col & 1023;
                int row0 = m0 + wm + i * 16 + lq * 4;
                if (mat == 0) {
#pragma unroll
                    for (int r = 0; r < 4; r++) out_q[(size_t)(row0 + r) * 1024 + cc] = f2bf(acc[i][j][r]);
                } else if (mat == 1) {
#pragma unroll
                    for (int r = 0; r < 4; r++) out_k[(size_t)(row0 + r) * 1024 + cc] = f2bf(acc[i][j][r]);
                } else {
                    ushort4 uv;
                    uv.x = f2bf(acc[i][j][0]); uv.y = f2bf(acc[i][j][1]);
                    uv.z = f2bf(acc[i][j][2]); uv.w = f2bf(acc[i][j][3]);
                    *(ushort4*)(out_vt + (size_t)cc * 4096 + row0) = uv;  // vt[n][m]
                }
            }
    } else if (MODE == 1) {
#pragma unroll
        for (int i = 0; i < 4; i++)
#pragma unroll
            for (int j = 0; j < 4; j++) {
                int col = n0 + wn + j * 16 + lr;
                int row0 = m0 + wm + i * 16 + lq * 4;
#pragma unroll
                for (int r = 0; r < 4; r++) {
                    size_t idx = (size_t)(row0 + r) * 1024 + col;
                    float v = acc[i][j][r] + resid[idx];
                    out_f32[idx] = v;
                    out_bf[idx] = f2bf(v);
                }
            }
    } else if (MODE == 2) {
#pragma unroll
        for (int i = 0; i < 4; i++)
#pragma unroll
            for (int j = 0; j < 4; j++) {
                int col = n0 + wn + j * 16 + lr;
                int rl0 = m0 + wm + i * 16 + lq * 4;
                float bv = bias[(size_t)e * 4096 + col];
#pragma unroll
                for (int r = 0; r < 4; r++) {
                    if (rl0 + r < cnt)
                        out_bf[(size_t)(off + rl0 + r) * 4096 + col] = f2bf(gelu_tanh(acc[i][j][r] + bv));
                }
            }
    } else {
#pragma unroll
        for (int i = 0; i < 4; i++)
#pragma unroll
            for (int j = 0; j < 4; j++) {
                int col = n0 + wn + j * 16 + lr;
                int rl0 = m0 + wm + i * 16 + lq * 4;
                float bv = bias[(size_t)e * 1024 + col];
#pragma unroll
                for (int r = 0; r < 4; r++) {
                    if (rl0 + r < cnt)
                        out_f32[(size_t)(off + rl0 + r) * 1024 + col] = acc[i][j][r] + bv;
                }
            }
    }
}

// ---------------------------------------------------------------------------
// Flash attention, bf16 MFMA. Grid (S/64, H, B), 256 threads = 4 waves.
// Each wave owns a 16-row Q strip. Online softmax fully in registers
// (row = (lane>>4)*4 + reg matches C/D layout). P -> LDS -> A-layout.
// ---------------------------------------------------------------------------
__global__ __launch_bounds__(256) void attn_mfma(const u16* __restrict__ qb,
                                                 const u16* __restrict__ kb,
                                                 const u16* __restrict__ vt,
                                                 u16* __restrict__ aob) {
    __shared__ u16 qs[64][72], ks[64][72], vs[64][72], ps[64][72];
    const int q0 = blockIdx.x * 64, h = blockIdx.y, b = blockIdx.z;
    const int tid = threadIdx.x, w = tid >> 6, lane = tid & 63;
    const int lr = lane & 15, lq = lane >> 4;
    const int ms = w * 16;
    const size_t tok0 = (size_t)b * Sc;

#pragma unroll
    for (int i = 0; i < 2; i++) {
        int c = tid + i * 256;
        int row = c >> 3, d8 = (c & 7) * 8;
        *(uint4*)&qs[row][d8] = *(const uint4*)(qb + (tok0 + q0 + row) * 1024 + h * 64 + d8);
    }
    __syncthreads();
    short8 qa[2];
    qa[0] = *(const short8*)&qs[ms + lr][lq * 8];
    qa[1] = *(const short8*)&qs[ms + lr][32 + lq * 8];

    floatx4 oacc[4];
    float m_r[4], l_r[4];
#pragma unroll
    for (int d4 = 0; d4 < 4; d4++) oacc[d4] = (floatx4){0.f, 0.f, 0.f, 0.f};
#pragma unroll
    for (int r = 0; r < 4; r++) { m_r[r] = -1e30f; l_r[r] = 0.f; }

    for (int kt = 0; kt < Sc / 64; kt++) {
        int k0 = kt * 64;
        __syncthreads();
#pragma unroll
        for (int i = 0; i < 2; i++) {
            int c = tid + i * 256;
            int row = c >> 3, d8 = (c & 7) * 8;
            *(uint4*)&ks[row][d8] = *(const uint4*)(kb + (tok0 + k0 + row) * 1024 + h * 64 + d8);
            *(uint4*)&vs[row][d8] = *(const uint4*)(vt + (size_t)(h * 64 + row) * 4096 + tok0 + k0 + d8);
        }
        __syncthreads();
        // S = Q K^T  (16 rows x 64 cols per wave)
        floatx4 sfr[4];
#pragma unroll
        for (int j4 = 0; j4 < 4; j4++) {
            short8 kf0 = *(const short8*)&ks[j4 * 16 + lr][lq * 8];
            short8 kf1 = *(const short8*)&ks[j4 * 16 + lr][32 + lq * 8];
            floatx4 sa = (floatx4){0.f, 0.f, 0.f, 0.f};
            sa = __builtin_amdgcn_mfma_f32_16x16x32_bf16(qa[0], kf0, sa, 0, 0, 0);
            sa = __builtin_amdgcn_mfma_f32_16x16x32_bf16(qa[1], kf1, sa, 0, 0, 0);
            sfr[j4] = sa * 0.125f;  // 1/sqrt(64)
        }
        // online softmax per row (reg r owns row lq*4+r)
#pragma unroll
        for (int r = 0; r < 4; r++) {
            float mx = fmaxf(fmaxf(sfr[0][r], sfr[1][r]), fmaxf(sfr[2][r], sfr[3][r]));
            mx = fmaxf(mx, __shfl_xor(mx, 1, 64));
            mx = fmaxf(mx, __shfl_xor(mx, 2, 64));
            mx = fmaxf(mx, __shfl_xor(mx, 4, 64));
            mx = fmaxf(mx, __shfl_xor(mx, 8, 64));
            float mn = fmaxf(m_r[r], mx);
            float alpha = __expf(m_r[r] - mn);
            m_r[r] = mn;
            float rs = 0.f;
#pragma unroll
            for (int j4 = 0; j4 < 4; j4++) {
                float p = __expf(sfr[j4][r] - mn);
                sfr[j4][r] = p;
                rs += p;
            }
            rs += __shfl_xor(rs, 1, 64);
            rs += __shfl_xor(rs, 2, 64);
            rs += __shfl_xor(rs, 4, 64);
            rs += __shfl_xor(rs, 8, 64);
            l_r[r] = l_r[r] * alpha + rs;
#pragma unroll
            for (int d4 = 0; d4 < 4; d4++) oacc[d4][r] *= alpha;
        }
        // write P (bf16) to LDS in C layout
#pragma unroll
        for (int j4 = 0; j4 < 4; j4++)
#pragma unroll
            for (int r = 0; r < 4; r++)
                ps[ms + lq * 4 + r][j4 * 16 + lr] = f2bf(sfr[j4][r]);
        __syncthreads();
        // P (A-layout) @ V^T
        short8 pa0 = *(const short8*)&ps[ms + lr][lq * 8];
        short8 pa1 = *(const short8*)&ps[ms + lr][32 + lq * 8];
#pragma unroll
        for (int d4 = 0; d4 < 4; d4++) {
            short8 vf0 = *(const short8*)&vs[d4 * 16 + lr][lq * 8];
            short8 vf1 = *(const short8*)&vs[d4 * 16 + lr][32 + lq * 8];
            oacc[d4] = __builtin_amdgcn_mfma_f32_16x16x32_bf16(pa0, vf0, oacc[d4], 0, 0, 0);
            oacc[d4] = __builtin_amdgcn_mfma_f32_16x16x32_bf16(pa1, vf1, oacc[d4], 0, 0, 0);
        }
    }
#pragma unroll
    for (int r = 0; r < 4; r++) {
        float inv = 1.0f / l_r[r];
        size_t row = tok0 + q0 + ms + lq * 4 + r;
#pragma unroll
        for (int d4 = 0; d4 < 4; d4++)
            aob[row * 1024 + h * 64 + d4 * 16 + lr] = f2bf(oacc[d4][r] * inv);
    }
}

// ---------------------------------------------------------------------------
// Router (fp32 x2), top-2, renorm; counts via atomics.
// ---------------------------------------------------------------------------
__global__ __launch_bounds__(256) void router_kernel(const float* __restrict__ x2,
                                                     const float* __restrict__ Wg,
                                                     int* __restrict__ topi,
                                                     float* __restrict__ topw,
                                                     int* __restrict__ counts) {
    int t = blockIdx.x, tid = threadIdx.x;
    float p[Ec] = {};
    const float* xr = x2 + (size_t)t * Dc;
    for (int k = tid; k < Dc; k += 256) {
        float xv = xr[k];
        const float* wr = Wg + (size_t)k * Ec;
#pragma unroll
        for (int e = 0; e < Ec; e++) p[e] += xv * wr[e];
    }
    __shared__ float red[256 * Ec];
#pragma unroll
    for (int e = 0; e < Ec; e++) red[tid * Ec + e] = p[e];
    __syncthreads();
    for (int off = 128; off > 0; off >>= 1) {
        if (tid < off) {
#pragma unroll
            for (int e = 0; e < Ec; e++) red[tid * Ec + e] += red[(tid + off) * Ec + e];
        }
        __syncthreads();
    }
    if (tid == 0) {
        float l[Ec];
        float mx = -1e30f;
#pragma unroll
        for (int e = 0; e < Ec; e++) { l[e] = red[e]; mx = fmaxf(mx, l[e]); }
#pragma unroll
        for (int e = 0; e < Ec; e++) l[e] = __expf(l[e] - mx);
        int i0 = 0;
#pragma unroll
        for (int e = 1; e < Ec; e++) if (l[e] > l[i0]) i0 = e;
        int i1 = (i0 == 0) ? 1 : 0;
#pragma unroll
        for (int e = 0; e < Ec; e++) if (e != i0 && l[e] > l[i1]) i1 = e;
        float v0 = l[i0], v1 = l[i1];
        float inv = 1.0f / (v0 + v1);
        topi[t * 2 + 0] = i0;
        topi[t * 2 + 1] = i1;
        topw[t * 2 + 0] = v0 * inv;
        topw[t * 2 + 1] = v1 * inv;
        atomicAdd(&counts[i0], 1);
        atomicAdd(&counts[i1], 1);
    }
}

__global__ void zero_small(int* counts, int* cursor) {
    int i = threadIdx.x;
    if (i < Ec) { counts[i] = 0; cursor[i] = 0; }
}

__global__ void scan_kernel(const int* counts, int* offsets) {
    if (threadIdx.x == 0) {
        int s = 0;
        for (int e = 0; e < Ec; e++) { offsets[e] = s; s += counts[e]; }
    }
}

__global__ __launch_bounds__(256) void scatter_kernel(const int* __restrict__ topi,
                                                      const int* __restrict__ offsets,
                                                      int* __restrict__ cursor,
                                                      int* __restrict__ list_tok,
                                                      int* __restrict__ slot_of) {
    int t = blockIdx.x * 256 + threadIdx.x;
    if (t >= NTOK) return;
    for (int s2 = 0; s2 < 2; s2++) {
        int e = topi[t * 2 + s2];
        int p = offsets[e] + atomicAdd(&cursor[e], 1);
        list_tok[p] = t;
        slot_of[t * 2 + s2] = p;
    }
}

// out[t] = x2[t] + w0*h2[slot0] + w1*h2[slot1]
__global__ __launch_bounds__(256) void combine_kernel(const float* __restrict__ x2,
                                                      const float* __restrict__ h2,
                                                      const int* __restrict__ slot_of,
                                                      const float* __restrict__ topw,
                                                      float* __restrict__ out) {
    int t = blockIdx.x, c = threadIdx.x;
    int s0 = slot_of[t * 2], s1 = slot_of[t * 2 + 1];
    float w0 = topw[t * 2], w1 = topw[t * 2 + 1];
    float4 a = ((const float4*)(x2 + (size_t)t * Dc))[c];
    float4 h0 = ((const float4*)(h2 + (size_t)s0 * Dc))[c];
    float4 h1 = ((const float4*)(h2 + (size_t)s1 * Dc))[c];
    float4 o;
    o.x = a.x + w0 * h0.x + w1 * h1.x;
    o.y = a.y + w0 * h0.y + w1 * h1.y;
    o.z = a.z + w0 * h0.z + w1 * h1.z;
    o.w = a.w + w0 * h0.w + w1 * h1.w;
    ((float4*)(out + (size_t)t * Dc))[c] = o;
}

// ---------------------------------------------------------------------------
// Workspace layout (MB):
//  [0,16)    x2 fp32        [16,24)  x2b bf16      [24,32)  hb bf16
//  [32,38)   wqkvT bf16     [38,40)  woT bf16
//  [40,48)   qb  [48,56) kb  [56,64) vt  [64,72) aob
//  [72,136)  w1T bf16       [136,200) w2T bf16
//  [200,264) h1 bf16        [264,296) h2 fp32
//  [296..)   router scratch
// ---------------------------------------------------------------------------
extern "C" void kernel_launch(void* const* d_in, const int* in_sizes, int n_in,
                              void* d_out, int out_size, void* d_ws, size_t ws_size,
                              hipStream_t stream) {
    const float* x    = (const float*)d_in[0];
    const float* ln_g = (const float*)d_in[1];
    const float* ln_b = (const float*)d_in[2];
    const float* Wq   = (const float*)d_in[3];
    const float* Wk   = (const float*)d_in[4];
    const float* Wv   = (const float*)d_in[5];
    const float* Wo   = (const float*)d_in[6];
    const float* Wg   = (const float*)d_in[7];
    const float* W1   = (const float*)d_in[8];
    const float* b1   = (const float*)d_in[9];
    const float* W2   = (const float*)d_in[10];
    const float* b2   = (const float*)d_in[11];
    float* out = (float*)d_out;

    char* ws = (char*)d_ws;
    const size_t MB = 1ull << 20;
    float* x2    = (float*)(ws + 0 * MB);
    u16* x2b     = (u16*)(ws + 16 * MB);
    u16* hb      = (u16*)(ws + 24 * MB);
    u16* wqkvT   = (u16*)(ws + 32 * MB);
    u16* woT     = (u16*)(ws + 38 * MB);
    u16* qb      = (u16*)(ws + 40 * MB);
    u16* kb      = (u16*)(ws + 48 * MB);
    u16* vt      = (u16*)(ws + 56 * MB);
    u16* aob     = (u16*)(ws + 64 * MB);
    u16* w1T     = (u16*)(ws + 72 * MB);
    u16* w2T     = (u16*)(ws + 136 * MB);
    u16* h1      = (u16*)(ws + 200 * MB);
    float* h2    = (float*)(ws + 264 * MB);
    char* sm     = ws + 296 * MB;
    float* topw    = (float*)(sm);
    int*   topi    = (int*)(sm + (1 << 15));
    int*   slot_of = (int*)(sm + 2 * (1 << 15));
    int*   list_tok= (int*)(sm + 3 * (1 << 15));
    int*   counts  = (int*)(sm + 4 * (1 << 15));
    int*   offsets = counts + 64;
    int*   cursor  = counts + 128;

    // weight transpose-casts
    tcast_kernel<<<dim3(16, 16, 1), 256, 0, stream>>>(Wq, wqkvT + 0 * 1024 * 1024, 1024, 1024, 0, 0);
    tcast_kernel<<<dim3(16, 16, 1), 256, 0, stream>>>(Wk, wqkvT + 1 * 1024 * 1024, 1024, 1024, 0, 0);
    tcast_kernel<<<dim3(16, 16, 1), 256, 0, stream>>>(Wv, wqkvT + 2 * 1024 * 1024, 1024, 1024, 0, 0);
    tcast_kernel<<<dim3(16, 16, 1), 256, 0, stream>>>(Wo, woT, 1024, 1024, 0, 0);
    tcast_kernel<<<dim3(64, 16, 8), 256, 0, stream>>>(W1, w1T, 1024, 4096,
                                                      (size_t)1024 * 4096, (size_t)4096 * 1024);
    tcast_kernel<<<dim3(16, 64, 8), 256, 0, stream>>>(W2, w2T, 4096, 1024,
                                                      (size_t)4096 * 1024, (size_t)1024 * 4096);

    // attention
    ln_kernel<<<NTOK, 256, 0, stream>>>(x, ln_g, ln_b, hb);
    gemm_mfma<0><<<dim3(24, 32), 256, 0, stream>>>(hb, wqkvT, NTOK, 3072, 1024,
                                                   qb, kb, vt, nullptr, nullptr, nullptr, nullptr,
                                                   nullptr, nullptr, nullptr);
    attn_mfma<<<dim3(Sc / 64, 16, 2), 256, 0, stream>>>(qb, kb, vt, aob);
    gemm_mfma<1><<<dim3(8, 32), 256, 0, stream>>>(aob, woT, NTOK, 1024, 1024,
                                                  nullptr, nullptr, nullptr, x, x2, x2b, nullptr,
                                                  nullptr, nullptr, nullptr);

    // routing
    zero_small<<<1, 64, 0, stream>>>(counts, cursor);
    router_kernel<<<NTOK, 256, 0, stream>>>(x2, Wg, topi, topw, counts);
    scan_kernel<<<1, 1, 0, stream>>>(counts, offsets);
    scatter_kernel<<<NTOK / 256, 256, 0, stream>>>(topi, offsets, cursor, list_tok, slot_of);

    // experts
    gemm_mfma<2><<<dim3(32, 32, 8), 256, 0, stream>>>(x2b, w1T, NTOK, 4096, 1024,
                                                      nullptr, nullptr, nullptr, nullptr, nullptr,
                                                      h1, b1, counts, offsets, list_tok);
    gemm_mfma<3><<<dim3(8, 32, 8), 256, 0, stream>>>(h1, w2T, NTOK, 1024, 4096,
                                                     nullptr, nullptr, nullptr, nullptr, h2,
                                                     nullptr, b2, counts, offsets, list_tok);
    combine_kernel<<<NTOK, 256, 0, stream>>>(x2, h2, slot_of, topw, out);
}

// Round 3
// 982.656 us; speedup vs baseline: 6.6116x; 1.6929x over previous
//
#include <hip/hip_runtime.h>
#include <hip/hip_bf16.h>

// AGIFORMERBlock: B=2, S=2048, D=1024, H=16 (dh=64), F=4096, E=8, K=2
constexpr int Sc = 2048;
constexpr int Dc = 1024;
constexpr int Fc = 4096;
constexpr int Ec = 8;
constexpr int NTOK = 4096;  // B*S

typedef __attribute__((ext_vector_type(8))) short short8;
typedef __attribute__((ext_vector_type(4))) float floatx4;
typedef unsigned short u16;

__device__ __forceinline__ u16 f2bf(float f) {
    __hip_bfloat16 h = __float2bfloat16(f);
    return *reinterpret_cast<u16*>(&h);
}

__device__ __forceinline__ float gelu_tanh(float x) {
    float x3 = x * x * x;
    float t = tanhf(0.79788456080286535588f * (x + 0.044715f * x3));
    return 0.5f * x * (1.0f + t);
}

// async global->LDS, 16B per lane; LDS dest = wave-uniform base + lane*16
__device__ __forceinline__ void async16(const u16* g, u16* l) {
    __builtin_amdgcn_global_load_lds(
        (const __attribute__((address_space(1))) unsigned int*)g,
        (__attribute__((address_space(3))) unsigned int*)l, 16, 0, 0);
}

// ---------------------------------------------------------------------------
// Transpose-cast: src fp32 [R][C] -> dst bf16 [C][R].  Grid (C/64, R/64, Z).
// ---------------------------------------------------------------------------
__global__ __launch_bounds__(256) void tcast_kernel(const float* __restrict__ src,
                                                    u16* __restrict__ dst,
                                                    int R, int C,
                                                    size_t sstride, size_t dstride) {
    __shared__ float t[64][65];
    const float* s = src + (size_t)blockIdx.z * sstride;
    u16* d = dst + (size_t)blockIdx.z * dstride;
    int r0 = blockIdx.y * 64, c0 = blockIdx.x * 64;
    int tid = threadIdx.x;
#pragma unroll
    for (int i = 0; i < 4; i++) {
        int c = tid + i * 256;
        int row = c >> 4, col4 = (c & 15) * 4;
        float4 v = *(const float4*)(s + (size_t)(r0 + row) * C + c0 + col4);
        t[row][col4 + 0] = v.x;
        t[row][col4 + 1] = v.y;
        t[row][col4 + 2] = v.z;
        t[row][col4 + 3] = v.w;
    }
    __syncthreads();
#pragma unroll
    for (int i = 0; i < 2; i++) {
        int c = tid + i * 256;
        int dr = c >> 3, m8 = (c & 7) * 8;
        union { u16 us[8]; uint4 v; } pk;
#pragma unroll
        for (int j = 0; j < 8; j++) pk.us[j] = f2bf(t[m8 + j][dr]);
        *(uint4*)(d + (size_t)(c0 + dr) * R + r0 + m8) = pk.v;
    }
}

// ---------------------------------------------------------------------------
// bf16 transpose: src [R][C] -> dst [C][R]. Grid (C/64, R/64).
// ---------------------------------------------------------------------------
__global__ __launch_bounds__(256) void btrans_kernel(const u16* __restrict__ src,
                                                     u16* __restrict__ dst,
                                                     int R, int C) {
    __shared__ u16 t[64][72];
    int r0 = blockIdx.y * 64, c0 = blockIdx.x * 64;
    int tid = threadIdx.x;
#pragma unroll
    for (int i = 0; i < 2; i++) {
        int c = tid + i * 256;
        int row = c >> 3, s8 = (c & 7) * 8;
        *(uint4*)&t[row][s8] = *(const uint4*)(src + (size_t)(r0 + row) * C + c0 + s8);
    }
    __syncthreads();
#pragma unroll
    for (int i = 0; i < 2; i++) {
        int c = tid + i * 256;
        int row = c >> 3, s8 = (c & 7) * 8;
        union { u16 us[8]; uint4 v; } pk;
#pragma unroll
        for (int j = 0; j < 8; j++) pk.us[j] = t[s8 + j][row];
        *(uint4*)(dst + (size_t)(c0 + row) * R + r0 + s8) = pk.v;
    }
}

// ---------------------------------------------------------------------------
// LayerNorm -> bf16. One block per row, 256 threads, D=1024.
// ---------------------------------------------------------------------------
__global__ __launch_bounds__(256) void ln_kernel(const float* __restrict__ x,
                                                 const float* __restrict__ g,
                                                 const float* __restrict__ b,
                                                 u16* __restrict__ hb) {
    int row = blockIdx.x, tid = threadIdx.x;
    const float* xr = x + (size_t)row * Dc;
    float4 xv = ((const float4*)xr)[tid];
    float s = xv.x + xv.y + xv.z + xv.w;
    float ss = xv.x * xv.x + xv.y * xv.y + xv.z * xv.z + xv.w * xv.w;
    __shared__ float r1[256], r2[256];
    r1[tid] = s; r2[tid] = ss;
    __syncthreads();
    for (int off = 128; off > 0; off >>= 1) {
        if (tid < off) { r1[tid] += r1[tid + off]; r2[tid] += r2[tid + off]; }
        __syncthreads();
    }
    float mean = r1[0] * (1.0f / Dc);
    float var = r2[0] * (1.0f / Dc) - mean * mean;
    float rs = rsqrtf(var + 1e-5f);
    float4 gv = ((const float4*)g)[tid];
    float4 bv = ((const float4*)b)[tid];
    ushort4 o;
    o.x = f2bf((xv.x - mean) * rs * gv.x + bv.x);
    o.y = f2bf((xv.y - mean) * rs * gv.y + bv.y);
    o.z = f2bf((xv.z - mean) * rs * gv.z + bv.z);
    o.w = f2bf((xv.w - mean) * rs * gv.w + bv.w);
    *(ushort4*)(hb + (size_t)row * Dc + tid * 4) = o;
}

// ---------------------------------------------------------------------------
// bf16 MFMA GEMM, m97 structure: 128x128 tile, BK=32, async global_load_lds
// staging into unpadded LDS with k-segment XOR swizzle; 4 waves, 4x4 frags.
// MODE 0: QKV fused (N=3072; q/k/v row-major by n0>>10)
// MODE 1: O-proj + residual -> x2 fp32 + x2b bf16
// MODE 2: MoE GEMM1, gathered A rows; gelu(acc+b1) -> h1 bf16
// MODE 3: MoE GEMM2; acc+b2 -> h2 fp32
// ---------------------------------------------------------------------------
template <int MODE>
__global__ __launch_bounds__(256) void gemm_mfma(
    const u16* __restrict__ A, const u16* __restrict__ BT,
    int N, int K,
    u16* __restrict__ out_q, u16* __restrict__ out_k, u16* __restrict__ out_v,
    const float* __restrict__ resid, float* __restrict__ out_f32,
    u16* __restrict__ out_bf, const float* __restrict__ bias,
    const int* __restrict__ counts, const int* __restrict__ offsets,
    const int* __restrict__ list_tok) {
    int e = 0, cnt = 0, off = 0;
    if (MODE >= 2) {
        e = blockIdx.z;
        cnt = counts[e];
        if ((int)blockIdx.y * 128 >= cnt) return;
        off = offsets[e];
    }
    const int tid = threadIdx.x;
    const int m0 = blockIdx.y * 128, n0 = blockIdx.x * 128;
    __shared__ u16 As[128][32];
    __shared__ u16 Bs[128][32];
    __shared__ int toksL[128];
    if (MODE == 2) {
        if (tid < 128) toksL[tid] = list_tok[off + min(m0 + tid, cnt - 1)];
        __syncthreads();
    }
    const u16* Bbase = BT + (MODE >= 2 ? (size_t)e * (size_t)N * K : 0);
    const int w = tid >> 6, lane = tid & 63;
    const int wm = (w >> 1) * 64, wn = (w & 1) * 64;
    const int lr = lane & 15, lq = lane >> 4;

    // staging: wave w deposits rows [w*32, w*32+32) of each tile, 2 instrs x 16 rows.
    // lane i -> row = base + (i>>2), LDS seg = i&3; global seg xor-swizzled.
    const int rA0 = w * 32 + (lane >> 2), rA1 = rA0 + 16;
    const int gsegu = (((lane & 3) ^ ((lane >> 3) & 3))) * 8;  // u16 units
    size_t ra0, ra1;
    if (MODE == 2) {
        ra0 = (size_t)toksL[rA0] * K;
        ra1 = (size_t)toksL[rA1] * K;
    } else if (MODE == 3) {
        ra0 = (size_t)(off + min(m0 + rA0, cnt - 1)) * K;
        ra1 = (size_t)(off + min(m0 + rA1, cnt - 1)) * K;
    } else {
        ra0 = (size_t)(m0 + rA0) * K;
        ra1 = (size_t)(m0 + rA1) * K;
    }
    const u16* gA0 = A + ra0 + gsegu;
    const u16* gA1 = A + ra1 + gsegu;
    const u16* gB0 = Bbase + (size_t)(n0 + rA0) * K + gsegu;
    const u16* gB1 = Bbase + (size_t)(n0 + rA1) * K + gsegu;
    u16* ldsA0 = &As[w * 32][0];
    u16* ldsA1 = &As[w * 32 + 16][0];
    u16* ldsB0 = &Bs[w * 32][0];
    u16* ldsB1 = &Bs[w * 32 + 16][0];

    // frag LDS pointers (K-invariant): seg swizzle f(row) = (lr>>1)&3
    const int fs = (lq ^ ((lr >> 1) & 3)) * 8;
    const u16* apt[4];
    const u16* bpt[4];
#pragma unroll
    for (int i = 0; i < 4; i++) {
        apt[i] = &As[wm + i * 16 + lr][fs];
        bpt[i] = &Bs[wn + i * 16 + lr][fs];
    }

    floatx4 acc[4][4];
#pragma unroll
    for (int i = 0; i < 4; i++)
#pragma unroll
        for (int j = 0; j < 4; j++) acc[i][j] = (floatx4){0.f, 0.f, 0.f, 0.f};

    for (int k0 = 0; k0 < K; k0 += 32) {
        async16(gA0 + k0, ldsA0);
        async16(gA1 + k0, ldsA1);
        async16(gB0 + k0, ldsB0);
        async16(gB1 + k0, ldsB1);
        __syncthreads();
        short8 af[4], bfr[4];
#pragma unroll
        for (int i = 0; i < 4; i++) af[i] = *(const short8*)apt[i];
#pragma unroll
        for (int j = 0; j < 4; j++) bfr[j] = *(const short8*)bpt[j];
#pragma unroll
        for (int i = 0; i < 4; i++)
#pragma unroll
            for (int j = 0; j < 4; j++)
                acc[i][j] = __builtin_amdgcn_mfma_f32_16x16x32_bf16(af[i], bfr[j], acc[i][j], 0, 0, 0);
        __syncthreads();
    }

    // Epilogue. C/D layout: col = lane&15, row = (lane>>4)*4 + reg.
    if (MODE == 0) {
        int mat = n0 >> 10;  // block-uniform
        u16* dst = (mat == 0) ? out_q : (mat == 1 ? out_k : out_v);
#pragma unroll
        for (int i = 0; i < 4; i++)
#pragma unroll
            for (int j = 0; j < 4; j++) {
                int cc = (n0 + wn + j * 16 + lr) & 1023;
                int row0 = m0 + wm + i * 16 + lq * 4;
#pragma unroll
                for (int r = 0; r < 4; r++)
                    dst[(size_t)(row0 + r) * 1024 + cc] = f2bf(acc[i][j][r]);
            }
    } else if (MODE == 1) {
#pragma unroll
        for (int i = 0; i < 4; i++)
#pragma unroll
            for (int j = 0; j < 4; j++) {
                int col = n0 + wn + j * 16 + lr;
                int row0 = m0 + wm + i * 16 + lq * 4;
#pragma unroll
                for (int r = 0; r < 4; r++) {
                    size_t idx = (size_t)(row0 + r) * 1024 + col;
                    float v = acc[i][j][r] + resid[idx];
                    out_f32[idx] = v;
                    out_bf[idx] = f2bf(v);
                }
            }
    } else if (MODE == 2) {
#pragma unroll
        for (int i = 0; i < 4; i++)
#pragma unroll
            for (int j = 0; j < 4; j++) {
                int col = n0 + wn + j * 16 + lr;
                int rl0 = m0 + wm + i * 16 + lq * 4;
                float bv = bias[(size_t)e * 4096 + col];
#pragma unroll
                for (int r = 0; r < 4; r++) {
                    if (rl0 + r < cnt)
                        out_bf[(size_t)(off + rl0 + r) * 4096 + col] = f2bf(gelu_tanh(acc[i][j][r] + bv));
                }
            }
    } else {
#pragma unroll
        for (int i = 0; i < 4; i++)
#pragma unroll
            for (int j = 0; j < 4; j++) {
                int col = n0 + wn + j * 16 + lr;
                int rl0 = m0 + wm + i * 16 + lq * 4;
                float bv = bias[(size_t)e * 1024 + col];
#pragma unroll
                for (int r = 0; r < 4; r++) {
                    if (rl0 + r < cnt)
                        out_f32[(size_t)(off + rl0 + r) * 1024 + col] = acc[i][j][r] + bv;
                }
            }
    }
}

// ---------------------------------------------------------------------------
// Flash attention, bf16 MFMA. Grid (S/64, H, B), 256 threads = 4 waves.
// ---------------------------------------------------------------------------
__global__ __launch_bounds__(256) void attn_mfma(const u16* __restrict__ qb,
                                                 const u16* __restrict__ kb,
                                                 const u16* __restrict__ vt,
                                                 u16* __restrict__ aob) {
    __shared__ u16 qs[64][72], ks[64][72], vs[64][72], ps[64][72];
    const int q0 = blockIdx.x * 64, h = blockIdx.y, b = blockIdx.z;
    const int tid = threadIdx.x, w = tid >> 6, lane = tid & 63;
    const int lr = lane & 15, lq = lane >> 4;
    const int ms = w * 16;
    const size_t tok0 = (size_t)b * Sc;

#pragma unroll
    for (int i = 0; i < 2; i++) {
        int c = tid + i * 256;
        int row = c >> 3, d8 = (c & 7) * 8;
        *(uint4*)&qs[row][d8] = *(const uint4*)(qb + (tok0 + q0 + row) * 1024 + h * 64 + d8);
    }
    __syncthreads();
    short8 qa[2];
    qa[0] = *(const short8*)&qs[ms + lr][lq * 8];
    qa[1] = *(const short8*)&qs[ms + lr][32 + lq * 8];

    floatx4 oacc[4];
    float m_r[4], l_r[4];
#pragma unroll
    for (int d4 = 0; d4 < 4; d4++) oacc[d4] = (floatx4){0.f, 0.f, 0.f, 0.f};
#pragma unroll
    for (int r = 0; r < 4; r++) { m_r[r] = -1e30f; l_r[r] = 0.f; }

    for (int kt = 0; kt < Sc / 64; kt++) {
        int k0 = kt * 64;
        __syncthreads();
#pragma unroll
        for (int i = 0; i < 2; i++) {
            int c = tid + i * 256;
            int row = c >> 3, d8 = (c & 7) * 8;
            *(uint4*)&ks[row][d8] = *(const uint4*)(kb + (tok0 + k0 + row) * 1024 + h * 64 + d8);
            *(uint4*)&vs[row][d8] = *(const uint4*)(vt + (size_t)(h * 64 + row) * 4096 + tok0 + k0 + d8);
        }
        __syncthreads();
        floatx4 sfr[4];
#pragma unroll
        for (int j4 = 0; j4 < 4; j4++) {
            short8 kf0 = *(const short8*)&ks[j4 * 16 + lr][lq * 8];
            short8 kf1 = *(const short8*)&ks[j4 * 16 + lr][32 + lq * 8];
            floatx4 sa = (floatx4){0.f, 0.f, 0.f, 0.f};
            sa = __builtin_amdgcn_mfma_f32_16x16x32_bf16(qa[0], kf0, sa, 0, 0, 0);
            sa = __builtin_amdgcn_mfma_f32_16x16x32_bf16(qa[1], kf1, sa, 0, 0, 0);
            sfr[j4] = sa * 0.125f;
        }
#pragma unroll
        for (int r = 0; r < 4; r++) {
            float mx = fmaxf(fmaxf(sfr[0][r], sfr[1][r]), fmaxf(sfr[2][r], sfr[3][r]));
            mx = fmaxf(mx, __shfl_xor(mx, 1, 64));
            mx = fmaxf(mx, __shfl_xor(mx, 2, 64));
            mx = fmaxf(mx, __shfl_xor(mx, 4, 64));
            mx = fmaxf(mx, __shfl_xor(mx, 8, 64));
            float mn = fmaxf(m_r[r], mx);
            float alpha = __expf(m_r[r] - mn);
            m_r[r] = mn;
            float rs = 0.f;
#pragma unroll
            for (int j4 = 0; j4 < 4; j4++) {
                float p = __expf(sfr[j4][r] - mn);
                sfr[j4][r] = p;
                rs += p;
            }
            rs += __shfl_xor(rs, 1, 64);
            rs += __shfl_xor(rs, 2, 64);
            rs += __shfl_xor(rs, 4, 64);
            rs += __shfl_xor(rs, 8, 64);
            l_r[r] = l_r[r] * alpha + rs;
#pragma unroll
            for (int d4 = 0; d4 < 4; d4++) oacc[d4][r] *= alpha;
        }
#pragma unroll
        for (int j4 = 0; j4 < 4; j4++)
#pragma unroll
            for (int r = 0; r < 4; r++)
                ps[ms + lq * 4 + r][j4 * 16 + lr] = f2bf(sfr[j4][r]);
        __syncthreads();
        short8 pa0 = *(const short8*)&ps[ms + lr][lq * 8];
        short8 pa1 = *(const short8*)&ps[ms + lr][32 + lq * 8];
#pragma unroll
        for (int d4 = 0; d4 < 4; d4++) {
            short8 vf0 = *(const short8*)&vs[d4 * 16 + lr][lq * 8];
            short8 vf1 = *(const short8*)&vs[d4 * 16 + lr][32 + lq * 8];
            oacc[d4] = __builtin_amdgcn_mfma_f32_16x16x32_bf16(pa0, vf0, oacc[d4], 0, 0, 0);
            oacc[d4] = __builtin_amdgcn_mfma_f32_16x16x32_bf16(pa1, vf1, oacc[d4], 0, 0, 0);
        }
    }
#pragma unroll
    for (int r = 0; r < 4; r++) {
        float inv = 1.0f / l_r[r];
        size_t row = tok0 + q0 + ms + lq * 4 + r;
#pragma unroll
        for (int d4 = 0; d4 < 4; d4++)
            aob[row * 1024 + h * 64 + d4 * 16 + lr] = f2bf(oacc[d4][r] * inv);
    }
}

// ---------------------------------------------------------------------------
// Router, scan, scatter, combine
// ---------------------------------------------------------------------------
__global__ __launch_bounds__(256) void router_kernel(const float* __restrict__ x2,
                                                     const float* __restrict__ Wg,
                                                     int* __restrict__ topi,
                                                     float* __restrict__ topw,
                                                     int* __restrict__ counts) {
    int t = blockIdx.x, tid = threadIdx.x;
    float p[Ec] = {};
    const float* xr = x2 + (size_t)t * Dc;
    for (int k = tid; k < Dc; k += 256) {
        float xv = xr[k];
        const float* wr = Wg + (size_t)k * Ec;
#pragma unroll
        for (int e = 0; e < Ec; e++) p[e] += xv * wr[e];
    }
    __shared__ float red[256 * Ec];
#pragma unroll
    for (int e = 0; e < Ec; e++) red[tid * Ec + e] = p[e];
    __syncthreads();
    for (int off = 128; off > 0; off >>= 1) {
        if (tid < off) {
#pragma unroll
            for (int e = 0; e < Ec; e++) red[tid * Ec + e] += red[(tid + off) * Ec + e];
        }
        __syncthreads();
    }
    if (tid == 0) {
        float l[Ec];
        float mx = -1e30f;
#pragma unroll
        for (int e = 0; e < Ec; e++) { l[e] = red[e]; mx = fmaxf(mx, l[e]); }
#pragma unroll
        for (int e = 0; e < Ec; e++) l[e] = __expf(l[e] - mx);
        int i0 = 0;
#pragma unroll
        for (int e = 1; e < Ec; e++) if (l[e] > l[i0]) i0 = e;
        int i1 = (i0 == 0) ? 1 : 0;
#pragma unroll
        for (int e = 0; e < Ec; e++) if (e != i0 && l[e] > l[i1]) i1 = e;
        float v0 = l[i0], v1 = l[i1];
        float inv = 1.0f / (v0 + v1);
        topi[t * 2 + 0] = i0;
        topi[t * 2 + 1] = i1;
        topw[t * 2 + 0] = v0 * inv;
        topw[t * 2 + 1] = v1 * inv;
        atomicAdd(&counts[i0], 1);
        atomicAdd(&counts[i1], 1);
    }
}

__global__ void zero_small(int* counts, int* cursor) {
    int i = threadIdx.x;
    if (i < Ec) { counts[i] = 0; cursor[i] = 0; }
}

__global__ void scan_kernel(const int* counts, int* offsets) {
    if (threadIdx.x == 0) {
        int s = 0;
        for (int e = 0; e < Ec; e++) { offsets[e] = s; s += counts[e]; }
    }
}

__global__ __launch_bounds__(256) void scatter_kernel(const int* __restrict__ topi,
                                                      const int* __restrict__ offsets,
                                                      int* __restrict__ cursor,
                                                      int* __restrict__ list_tok,
                                                      int* __restrict__ slot_of) {
    int t = blockIdx.x * 256 + threadIdx.x;
    if (t >= NTOK) return;
    for (int s2 = 0; s2 < 2; s2++) {
        int e = topi[t * 2 + s2];
        int p = offsets[e] + atomicAdd(&cursor[e], 1);
        list_tok[p] = t;
        slot_of[t * 2 + s2] = p;
    }
}

__global__ __launch_bounds__(256) void combine_kernel(const float* __restrict__ x2,
                                                      const float* __restrict__ h2,
                                                      const int* __restrict__ slot_of,
                                                      const float* __restrict__ topw,
                                                      float* __restrict__ out) {
    int t = blockIdx.x, c = threadIdx.x;
    int s0 = slot_of[t * 2], s1 = slot_of[t * 2 + 1];
    float w0 = topw[t * 2], w1 = topw[t * 2 + 1];
    float4 a = ((const float4*)(x2 + (size_t)t * Dc))[c];
    float4 h0 = ((const float4*)(h2 + (size_t)s0 * Dc))[c];
    float4 h1 = ((const float4*)(h2 + (size_t)s1 * Dc))[c];
    float4 o;
    o.x = a.x + w0 * h0.x + w1 * h1.x;
    o.y = a.y + w0 * h0.y + w1 * h1.y;
    o.z = a.z + w0 * h0.z + w1 * h1.z;
    o.w = a.w + w0 * h0.w + w1 * h1.w;
    ((float4*)(out + (size_t)t * Dc))[c] = o;
}

// ---------------------------------------------------------------------------
// Workspace (MB):
//  [0,16) x2 fp32   [16,24) x2b    [24,32) hb
//  [32,38) wqkvT    [38,40) woT
//  [40,48) qb  [48,56) kb  [56,64) vt  [64,72) vb->aob
//  [72,136) w1T     [136,200) w2T  [200,264) h1  [264,296) h2
//  [296..) router scratch
// ---------------------------------------------------------------------------
extern "C" void kernel_launch(void* const* d_in, const int* in_sizes, int n_in,
                              void* d_out, int out_size, void* d_ws, size_t ws_size,
                              hipStream_t stream) {
    const float* x    = (const float*)d_in[0];
    const float* ln_g = (const float*)d_in[1];
    const float* ln_b = (const float*)d_in[2];
    const float* Wq   = (const float*)d_in[3];
    const float* Wk   = (const float*)d_in[4];
    const float* Wv   = (const float*)d_in[5];
    const float* Wo   = (const float*)d_in[6];
    const float* Wg   = (const float*)d_in[7];
    const float* W1   = (const float*)d_in[8];
    const float* b1   = (const float*)d_in[9];
    const float* W2   = (const float*)d_in[10];
    const float* b2   = (const float*)d_in[11];
    float* out = (float*)d_out;

    char* ws = (char*)d_ws;
    const size_t MB = 1ull << 20;
    float* x2    = (float*)(ws + 0 * MB);
    u16* x2b     = (u16*)(ws + 16 * MB);
    u16* hb      = (u16*)(ws + 24 * MB);
    u16* wqkvT   = (u16*)(ws + 32 * MB);
    u16* woT     = (u16*)(ws + 38 * MB);
    u16* qb      = (u16*)(ws + 40 * MB);
    u16* kb      = (u16*)(ws + 48 * MB);
    u16* vt      = (u16*)(ws + 56 * MB);
    u16* vb      = (u16*)(ws + 64 * MB);  // dead after btrans; reused as aob
    u16* aob     = (u16*)(ws + 64 * MB);
    u16* w1T     = (u16*)(ws + 72 * MB);
    u16* w2T     = (u16*)(ws + 136 * MB);
    u16* h1      = (u16*)(ws + 200 * MB);
    float* h2    = (float*)(ws + 264 * MB);
    char* sm     = ws + 296 * MB;
    float* topw    = (float*)(sm);
    int*   topi    = (int*)(sm + (1 << 15));
    int*   slot_of = (int*)(sm + 2 * (1 << 15));
    int*   list_tok= (int*)(sm + 3 * (1 << 15));
    int*   counts  = (int*)(sm + 4 * (1 << 15));
    int*   offsets = counts + 64;
    int*   cursor  = counts + 128;

    // weight transpose-casts
    tcast_kernel<<<dim3(16, 16, 1), 256, 0, stream>>>(Wq, wqkvT + 0 * 1024 * 1024, 1024, 1024, 0, 0);
    tcast_kernel<<<dim3(16, 16, 1), 256, 0, stream>>>(Wk, wqkvT + 1 * 1024 * 1024, 1024, 1024, 0, 0);
    tcast_kernel<<<dim3(16, 16, 1), 256, 0, stream>>>(Wv, wqkvT + 2 * 1024 * 1024, 1024, 1024, 0, 0);
    tcast_kernel<<<dim3(16, 16, 1), 256, 0, stream>>>(Wo, woT, 1024, 1024, 0, 0);
    tcast_kernel<<<dim3(64, 16, 8), 256, 0, stream>>>(W1, w1T, 1024, 4096,
                                                      (size_t)1024 * 4096, (size_t)4096 * 1024);
    tcast_kernel<<<dim3(16, 64, 8), 256, 0, stream>>>(W2, w2T, 4096, 1024,
                                                      (size_t)4096 * 1024, (size_t)1024 * 4096);

    // attention
    ln_kernel<<<NTOK, 256, 0, stream>>>(x, ln_g, ln_b, hb);
    gemm_mfma<0><<<dim3(24, 32), 256, 0, stream>>>(hb, wqkvT, 3072, 1024,
                                                   qb, kb, vb, nullptr, nullptr, nullptr, nullptr,
                                                   nullptr, nullptr, nullptr);
    btrans_kernel<<<dim3(16, 64), 256, 0, stream>>>(vb, vt, 4096, 1024);
    attn_mfma<<<dim3(Sc / 64, 16, 2), 256, 0, stream>>>(qb, kb, vt, aob);
    gemm_mfma<1><<<dim3(8, 32), 256, 0, stream>>>(aob, woT, 1024, 1024,
                                                  nullptr, nullptr, nullptr, x, x2, x2b, nullptr,
                                                  nullptr, nullptr, nullptr);

    // routing
    zero_small<<<1, 64, 0, stream>>>(counts, cursor);
    router_kernel<<<NTOK, 256, 0, stream>>>(x2, Wg, topi, topw, counts);
    scan_kernel<<<1, 1, 0, stream>>>(counts, offsets);
    scatter_kernel<<<NTOK / 256, 256, 0, stream>>>(topi, offsets, cursor, list_tok, slot_of);

    // experts
    gemm_mfma<2><<<dim3(32, 32, 8), 256, 0, stream>>>(x2b, w1T, 4096, 1024,
                                                      nullptr, nullptr, nullptr, nullptr, nullptr,
                                                      h1, b1, counts, offsets, list_tok);
    gemm_mfma<3><<<dim3(8, 32, 8), 256, 0, stream>>>(h1, w2T, 1024, 4096,
                                                     nullptr, nullptr, nullptr, nullptr, h2,
                                                     nullptr, b2, counts, offsets, list_tok);
    combine_kernel<<<NTOK, 256, 0, stream>>>(x2, h2, slot_of, topw, out);
}

// Round 4
// 980.160 us; speedup vs baseline: 6.6284x; 1.0025x over previous
//
#include <hip/hip_runtime.h>
#include <hip/hip_bf16.h>

// AGIFORMERBlock: B=2, S=2048, D=1024, H=16 (dh=64), F=4096, E=8, K=2
constexpr int Sc = 2048;
constexpr int Dc = 1024;
constexpr int Fc = 4096;
constexpr int Ec = 8;
constexpr int NTOK = 4096;  // B*S

typedef __attribute__((ext_vector_type(8))) short short8;
typedef __attribute__((ext_vector_type(4))) float floatx4;
typedef unsigned short u16;

__device__ __forceinline__ u16 f2bf(float f) {
    __hip_bfloat16 h = __float2bfloat16(f);
    return *reinterpret_cast<u16*>(&h);
}

// tanh-gelu via sigmoid identity: 0.5x(1+tanh(y)) = x * 1/(1+exp(-2y)),
// y = 0.79788456(x + 0.044715 x^3)  ->  -2y = x*(-1.59576912 - 0.07135481 x^2)
__device__ __forceinline__ float gelu_fast(float x) {
    float x2 = x * x;
    float z = x * fmaf(-0.07135481282f, x2, -1.5957691216057308f);
    float e = __expf(z);
    return x * __builtin_amdgcn_rcpf(1.0f + e);
}

// async global->LDS, 16B per lane; LDS dest = wave-uniform base + lane*16
__device__ __forceinline__ void async16(const u16* g, u16* l) {
    __builtin_amdgcn_global_load_lds(
        (const __attribute__((address_space(1))) unsigned int*)g,
        (__attribute__((address_space(3))) unsigned int*)l, 16, 0, 0);
}

// ---------------------------------------------------------------------------
// Transpose-cast: src fp32 [R][C] -> dst bf16 [C][R].  Grid (C/64, R/64, Z).
// ---------------------------------------------------------------------------
__global__ __launch_bounds__(256) void tcast_kernel(const float* __restrict__ src,
                                                    u16* __restrict__ dst,
                                                    int R, int C,
                                                    size_t sstride, size_t dstride) {
    __shared__ float t[64][65];
    const float* s = src + (size_t)blockIdx.z * sstride;
    u16* d = dst + (size_t)blockIdx.z * dstride;
    int r0 = blockIdx.y * 64, c0 = blockIdx.x * 64;
    int tid = threadIdx.x;
#pragma unroll
    for (int i = 0; i < 4; i++) {
        int c = tid + i * 256;
        int row = c >> 4, col4 = (c & 15) * 4;
        float4 v = *(const float4*)(s + (size_t)(r0 + row) * C + c0 + col4);
        t[row][col4 + 0] = v.x;
        t[row][col4 + 1] = v.y;
        t[row][col4 + 2] = v.z;
        t[row][col4 + 3] = v.w;
    }
    __syncthreads();
#pragma unroll
    for (int i = 0; i < 2; i++) {
        int c = tid + i * 256;
        int dr = c >> 3, m8 = (c & 7) * 8;
        union { u16 us[8]; uint4 v; } pk;
#pragma unroll
        for (int j = 0; j < 8; j++) pk.us[j] = f2bf(t[m8 + j][dr]);
        *(uint4*)(d + (size_t)(c0 + dr) * R + r0 + m8) = pk.v;
    }
}

// ---------------------------------------------------------------------------
// bf16 transpose: src [R][C] -> dst [C][R]. Grid (C/64, R/64).
// ---------------------------------------------------------------------------
__global__ __launch_bounds__(256) void btrans_kernel(const u16* __restrict__ src,
                                                     u16* __restrict__ dst,
                                                     int R, int C) {
    __shared__ u16 t[64][72];
    int r0 = blockIdx.y * 64, c0 = blockIdx.x * 64;
    int tid = threadIdx.x;
#pragma unroll
    for (int i = 0; i < 2; i++) {
        int c = tid + i * 256;
        int row = c >> 3, s8 = (c & 7) * 8;
        *(uint4*)&t[row][s8] = *(const uint4*)(src + (size_t)(r0 + row) * C + c0 + s8);
    }
    __syncthreads();
#pragma unroll
    for (int i = 0; i < 2; i++) {
        int c = tid + i * 256;
        int row = c >> 3, s8 = (c & 7) * 8;
        union { u16 us[8]; uint4 v; } pk;
#pragma unroll
        for (int j = 0; j < 8; j++) pk.us[j] = t[s8 + j][row];
        *(uint4*)(dst + (size_t)(c0 + row) * R + r0 + s8) = pk.v;
    }
}

// ---------------------------------------------------------------------------
// LayerNorm -> bf16. One block per row, 256 threads, D=1024.
// ---------------------------------------------------------------------------
__global__ __launch_bounds__(256) void ln_kernel(const float* __restrict__ x,
                                                 const float* __restrict__ g,
                                                 const float* __restrict__ b,
                                                 u16* __restrict__ hb) {
    int row = blockIdx.x, tid = threadIdx.x;
    const float* xr = x + (size_t)row * Dc;
    float4 xv = ((const float4*)xr)[tid];
    float s = xv.x + xv.y + xv.z + xv.w;
    float ss = xv.x * xv.x + xv.y * xv.y + xv.z * xv.z + xv.w * xv.w;
    __shared__ float r1[256], r2[256];
    r1[tid] = s; r2[tid] = ss;
    __syncthreads();
    for (int off = 128; off > 0; off >>= 1) {
        if (tid < off) { r1[tid] += r1[tid + off]; r2[tid] += r2[tid + off]; }
        __syncthreads();
    }
    float mean = r1[0] * (1.0f / Dc);
    float var = r2[0] * (1.0f / Dc) - mean * mean;
    float rs = rsqrtf(var + 1e-5f);
    float4 gv = ((const float4*)g)[tid];
    float4 bv = ((const float4*)b)[tid];
    ushort4 o;
    o.x = f2bf((xv.x - mean) * rs * gv.x + bv.x);
    o.y = f2bf((xv.y - mean) * rs * gv.y + bv.y);
    o.z = f2bf((xv.z - mean) * rs * gv.z + bv.z);
    o.w = f2bf((xv.w - mean) * rs * gv.w + bv.w);
    *(ushort4*)(hb + (size_t)row * Dc + tid * 4) = o;
}

// ---------------------------------------------------------------------------
// bf16 MFMA GEMM, m97 structure: 128x128 tile, BK=32, async global_load_lds
// staging into unpadded LDS with k-segment XOR swizzle; 4 waves, 4x4 frags.
// MODE 0: QKV fused (N=3072; q/k/v row-major by n0>>10)
// MODE 1: O-proj + residual -> x2 fp32 + x2b bf16
// MODE 2: MoE GEMM1, gathered A rows; gelu(acc+b1) -> h1 bf16
// MODE 3: MoE GEMM2; acc+b2 -> h2 fp32
// ---------------------------------------------------------------------------
template <int MODE>
__global__ __launch_bounds__(256) void gemm_mfma(
    const u16* __restrict__ A, const u16* __restrict__ BT,
    int N, int K,
    u16* __restrict__ out_q, u16* __restrict__ out_k, u16* __restrict__ out_v,
    const float* __restrict__ resid, float* __restrict__ out_f32,
    u16* __restrict__ out_bf, const float* __restrict__ bias,
    const int* __restrict__ counts, const int* __restrict__ offsets,
    const int* __restrict__ list_tok) {
    int e = 0, cnt = 0, off = 0;
    if (MODE >= 2) {
        e = blockIdx.z;
        cnt = counts[e];
        if ((int)blockIdx.y * 128 >= cnt) return;
        off = offsets[e];
    }
    const int tid = threadIdx.x;
    const int m0 = blockIdx.y * 128, n0 = blockIdx.x * 128;
    __shared__ u16 As[128][32];
    __shared__ u16 Bs[128][32];
    __shared__ int toksL[128];
    if (MODE == 2) {
        if (tid < 128) toksL[tid] = list_tok[off + min(m0 + tid, cnt - 1)];
        __syncthreads();
    }
    const u16* Bbase = BT + (MODE >= 2 ? (size_t)e * (size_t)N * K : 0);
    const int w = tid >> 6, lane = tid & 63;
    const int wm = (w >> 1) * 64, wn = (w & 1) * 64;
    const int lr = lane & 15, lq = lane >> 4;

    // staging: wave w deposits rows [w*32, w*32+32) of each tile.
    const int rA0 = w * 32 + (lane >> 2), rA1 = rA0 + 16;
    const int gsegu = (((lane & 3) ^ ((lane >> 3) & 3))) * 8;  // u16 units
    size_t ra0, ra1;
    if (MODE == 2) {
        ra0 = (size_t)toksL[rA0] * K;
        ra1 = (size_t)toksL[rA1] * K;
    } else if (MODE == 3) {
        ra0 = (size_t)(off + min(m0 + rA0, cnt - 1)) * K;
        ra1 = (size_t)(off + min(m0 + rA1, cnt - 1)) * K;
    } else {
        ra0 = (size_t)(m0 + rA0) * K;
        ra1 = (size_t)(m0 + rA1) * K;
    }
    const u16* gA0 = A + ra0 + gsegu;
    const u16* gA1 = A + ra1 + gsegu;
    const u16* gB0 = Bbase + (size_t)(n0 + rA0) * K + gsegu;
    const u16* gB1 = Bbase + (size_t)(n0 + rA1) * K + gsegu;
    u16* ldsA0 = &As[w * 32][0];
    u16* ldsA1 = &As[w * 32 + 16][0];
    u16* ldsB0 = &Bs[w * 32][0];
    u16* ldsB1 = &Bs[w * 32 + 16][0];

    // frag LDS pointers (K-invariant): seg swizzle f(row) = (lr>>1)&3
    const int fs = (lq ^ ((lr >> 1) & 3)) * 8;
    const u16* apt[4];
    const u16* bpt[4];
#pragma unroll
    for (int i = 0; i < 4; i++) {
        apt[i] = &As[wm + i * 16 + lr][fs];
        bpt[i] = &Bs[wn + i * 16 + lr][fs];
    }

    floatx4 acc[4][4];
#pragma unroll
    for (int i = 0; i < 4; i++)
#pragma unroll
        for (int j = 0; j < 4; j++) acc[i][j] = (floatx4){0.f, 0.f, 0.f, 0.f};

    for (int k0 = 0; k0 < K; k0 += 32) {
        async16(gA0 + k0, ldsA0);
        async16(gA1 + k0, ldsA1);
        async16(gB0 + k0, ldsB0);
        async16(gB1 + k0, ldsB1);
        __syncthreads();
        short8 af[4], bfr[4];
#pragma unroll
        for (int i = 0; i < 4; i++) af[i] = *(const short8*)apt[i];
#pragma unroll
        for (int j = 0; j < 4; j++) bfr[j] = *(const short8*)bpt[j];
#pragma unroll
        for (int i = 0; i < 4; i++)
#pragma unroll
            for (int j = 0; j < 4; j++)
                acc[i][j] = __builtin_amdgcn_mfma_f32_16x16x32_bf16(af[i], bfr[j], acc[i][j], 0, 0, 0);
        __syncthreads();
    }

    // Epilogue. C/D layout: col = lane&15, row = (lane>>4)*4 + reg.
    if (MODE == 0) {
        int mat = n0 >> 10;  // block-uniform
        u16* dst = (mat == 0) ? out_q : (mat == 1 ? out_k : out_v);
#pragma unroll
        for (int i = 0; i < 4; i++)
#pragma unroll
            for (int j = 0; j < 4; j++) {
                int cc = (n0 + wn + j * 16 + lr) & 1023;
                int row0 = m0 + wm + i * 16 + lq * 4;
#pragma unroll
                for (int r = 0; r < 4; r++)
                    dst[(size_t)(row0 + r) * 1024 + cc] = f2bf(acc[i][j][r]);
            }
    } else if (MODE == 1) {
#pragma unroll
        for (int i = 0; i < 4; i++)
#pragma unroll
            for (int j = 0; j < 4; j++) {
                int col = n0 + wn + j * 16 + lr;
                int row0 = m0 + wm + i * 16 + lq * 4;
#pragma unroll
                for (int r = 0; r < 4; r++) {
                    size_t idx = (size_t)(row0 + r) * 1024 + col;
                    float v = acc[i][j][r] + resid[idx];
                    out_f32[idx] = v;
                    out_bf[idx] = f2bf(v);
                }
            }
    } else if (MODE == 2) {
#pragma unroll
        for (int j = 0; j < 4; j++) {
            int col = n0 + wn + j * 16 + lr;
            float bv = bias[(size_t)e * 4096 + col];
#pragma unroll
            for (int i = 0; i < 4; i++) {
                int rl0 = m0 + wm + i * 16 + lq * 4;
#pragma unroll
                for (int r = 0; r < 4; r++) {
                    if (rl0 + r < cnt)
                        out_bf[(size_t)(off + rl0 + r) * 4096 + col] = f2bf(gelu_fast(acc[i][j][r] + bv));
                }
            }
        }
    } else {
#pragma unroll
        for (int j = 0; j < 4; j++) {
            int col = n0 + wn + j * 16 + lr;
            float bv = bias[(size_t)e * 1024 + col];
#pragma unroll
            for (int i = 0; i < 4; i++) {
                int rl0 = m0 + wm + i * 16 + lq * 4;
#pragma unroll
                for (int r = 0; r < 4; r++) {
                    if (rl0 + r < cnt)
                        out_f32[(size_t)(off + rl0 + r) * 1024 + col] = acc[i][j][r] + bv;
                }
            }
        }
    }
}

// ---------------------------------------------------------------------------
// Flash attention, bf16 MFMA. Grid (S/64, H, B), 256 threads = 4 waves.
// ---------------------------------------------------------------------------
__global__ __launch_bounds__(256) void attn_mfma(const u16* __restrict__ qb,
                                                 const u16* __restrict__ kb,
                                                 const u16* __restrict__ vt,
                                                 u16* __restrict__ aob) {
    __shared__ u16 qs[64][72], ks[64][72], vs[64][72], ps[64][72];
    const int q0 = blockIdx.x * 64, h = blockIdx.y, b = blockIdx.z;
    const int tid = threadIdx.x, w = tid >> 6, lane = tid & 63;
    const int lr = lane & 15, lq = lane >> 4;
    const int ms = w * 16;
    const size_t tok0 = (size_t)b * Sc;

#pragma unroll
    for (int i = 0; i < 2; i++) {
        int c = tid + i * 256;
        int row = c >> 3, d8 = (c & 7) * 8;
        *(uint4*)&qs[row][d8] = *(const uint4*)(qb + (tok0 + q0 + row) * 1024 + h * 64 + d8);
    }
    __syncthreads();
    short8 qa[2];
    qa[0] = *(const short8*)&qs[ms + lr][lq * 8];
    qa[1] = *(const short8*)&qs[ms + lr][32 + lq * 8];

    floatx4 oacc[4];
    float m_r[4], l_r[4];
#pragma unroll
    for (int d4 = 0; d4 < 4; d4++) oacc[d4] = (floatx4){0.f, 0.f, 0.f, 0.f};
#pragma unroll
    for (int r = 0; r < 4; r++) { m_r[r] = -1e30f; l_r[r] = 0.f; }

    for (int kt = 0; kt < Sc / 64; kt++) {
        int k0 = kt * 64;
        __syncthreads();
#pragma unroll
        for (int i = 0; i < 2; i++) {
            int c = tid + i * 256;
            int row = c >> 3, d8 = (c & 7) * 8;
            *(uint4*)&ks[row][d8] = *(const uint4*)(kb + (tok0 + k0 + row) * 1024 + h * 64 + d8);
            *(uint4*)&vs[row][d8] = *(const uint4*)(vt + (size_t)(h * 64 + row) * 4096 + tok0 + k0 + d8);
        }
        __syncthreads();
        floatx4 sfr[4];
#pragma unroll
        for (int j4 = 0; j4 < 4; j4++) {
            short8 kf0 = *(const short8*)&ks[j4 * 16 + lr][lq * 8];
            short8 kf1 = *(const short8*)&ks[j4 * 16 + lr][32 + lq * 8];
            floatx4 sa = (floatx4){0.f, 0.f, 0.f, 0.f};
            sa = __builtin_amdgcn_mfma_f32_16x16x32_bf16(qa[0], kf0, sa, 0, 0, 0);
            sa = __builtin_amdgcn_mfma_f32_16x16x32_bf16(qa[1], kf1, sa, 0, 0, 0);
            sfr[j4] = sa * 0.125f;
        }
#pragma unroll
        for (int r = 0; r < 4; r++) {
            float mx = fmaxf(fmaxf(sfr[0][r], sfr[1][r]), fmaxf(sfr[2][r], sfr[3][r]));
            mx = fmaxf(mx, __shfl_xor(mx, 1, 64));
            mx = fmaxf(mx, __shfl_xor(mx, 2, 64));
            mx = fmaxf(mx, __shfl_xor(mx, 4, 64));
            mx = fmaxf(mx, __shfl_xor(mx, 8, 64));
            float mn = fmaxf(m_r[r], mx);
            float alpha = __expf(m_r[r] - mn);
            m_r[r] = mn;
            float rs = 0.f;
#pragma unroll
            for (int j4 = 0; j4 < 4; j4++) {
                float p = __expf(sfr[j4][r] - mn);
                sfr[j4][r] = p;
                rs += p;
            }
            rs += __shfl_xor(rs, 1, 64);
            rs += __shfl_xor(rs, 2, 64);
            rs += __shfl_xor(rs, 4, 64);
            rs += __shfl_xor(rs, 8, 64);
            l_r[r] = l_r[r] * alpha + rs;
#pragma unroll
            for (int d4 = 0; d4 < 4; d4++) oacc[d4][r] *= alpha;
        }
#pragma unroll
        for (int j4 = 0; j4 < 4; j4++)
#pragma unroll
            for (int r = 0; r < 4; r++)
                ps[ms + lq * 4 + r][j4 * 16 + lr] = f2bf(sfr[j4][r]);
        __syncthreads();
        short8 pa0 = *(const short8*)&ps[ms + lr][lq * 8];
        short8 pa1 = *(const short8*)&ps[ms + lr][32 + lq * 8];
#pragma unroll
        for (int d4 = 0; d4 < 4; d4++) {
            short8 vf0 = *(const short8*)&vs[d4 * 16 + lr][lq * 8];
            short8 vf1 = *(const short8*)&vs[d4 * 16 + lr][32 + lq * 8];
            oacc[d4] = __builtin_amdgcn_mfma_f32_16x16x32_bf16(pa0, vf0, oacc[d4], 0, 0, 0);
            oacc[d4] = __builtin_amdgcn_mfma_f32_16x16x32_bf16(pa1, vf1, oacc[d4], 0, 0, 0);
        }
    }
#pragma unroll
    for (int r = 0; r < 4; r++) {
        float inv = 1.0f / l_r[r];
        size_t row = tok0 + q0 + ms + lq * 4 + r;
#pragma unroll
        for (int d4 = 0; d4 < 4; d4++)
            aob[row * 1024 + h * 64 + d4 * 16 + lr] = f2bf(oacc[d4][r] * inv);
    }
}

// ---------------------------------------------------------------------------
// Router, scan, scatter, combine
// ---------------------------------------------------------------------------
__global__ __launch_bounds__(256) void router_kernel(const float* __restrict__ x2,
                                                     const float* __restrict__ Wg,
                                                     int* __restrict__ topi,
                                                     float* __restrict__ topw,
                                                     int* __restrict__ counts) {
    int t = blockIdx.x, tid = threadIdx.x;
    float p[Ec] = {};
    const float* xr = x2 + (size_t)t * Dc;
    for (int k = tid; k < Dc; k += 256) {
        float xv = xr[k];
        const float* wr = Wg + (size_t)k * Ec;
#pragma unroll
        for (int e = 0; e < Ec; e++) p[e] += xv * wr[e];
    }
    __shared__ float red[256 * Ec];
#pragma unroll
    for (int e = 0; e < Ec; e++) red[tid * Ec + e] = p[e];
    __syncthreads();
    for (int off = 128; off > 0; off >>= 1) {
        if (tid < off) {
#pragma unroll
            for (int e = 0; e < Ec; e++) red[tid * Ec + e] += red[(tid + off) * Ec + e];
        }
        __syncthreads();
    }
    if (tid == 0) {
        float l[Ec];
        float mx = -1e30f;
#pragma unroll
        for (int e = 0; e < Ec; e++) { l[e] = red[e]; mx = fmaxf(mx, l[e]); }
#pragma unroll
        for (int e = 0; e < Ec; e++) l[e] = __expf(l[e] - mx);
        int i0 = 0;
#pragma unroll
        for (int e = 1; e < Ec; e++) if (l[e] > l[i0]) i0 = e;
        int i1 = (i0 == 0) ? 1 : 0;
#pragma unroll
        for (int e = 0; e < Ec; e++) if (e != i0 && l[e] > l[i1]) i1 = e;
        float v0 = l[i0], v1 = l[i1];
        float inv = 1.0f / (v0 + v1);
        topi[t * 2 + 0] = i0;
        topi[t * 2 + 1] = i1;
        topw[t * 2 + 0] = v0 * inv;
        topw[t * 2 + 1] = v1 * inv;
        atomicAdd(&counts[i0], 1);
        atomicAdd(&counts[i1], 1);
    }
}

__global__ void zero_small(int* counts, int* cursor) {
    int i = threadIdx.x;
    if (i < Ec) { counts[i] = 0; cursor[i] = 0; }
}

__global__ void scan_kernel(const int* counts, int* offsets) {
    if (threadIdx.x == 0) {
        int s = 0;
        for (int e = 0; e < Ec; e++) { offsets[e] = s; s += counts[e]; }
    }
}

__global__ __launch_bounds__(256) void scatter_kernel(const int* __restrict__ topi,
                                                      const int* __restrict__ offsets,
                                                      int* __restrict__ cursor,
                                                      int* __restrict__ list_tok,
                                                      int* __restrict__ slot_of) {
    int t = blockIdx.x * 256 + threadIdx.x;
    if (t >= NTOK) return;
    for (int s2 = 0; s2 < 2; s2++) {
        int e = topi[t * 2 + s2];
        int p = offsets[e] + atomicAdd(&cursor[e], 1);
        list_tok[p] = t;
        slot_of[t * 2 + s2] = p;
    }
}

__global__ __launch_bounds__(256) void combine_kernel(const float* __restrict__ x2,
                                                      const float* __restrict__ h2,
                                                      const int* __restrict__ slot_of,
                                                      const float* __restrict__ topw,
                                                      float* __restrict__ out) {
    int t = blockIdx.x, c = threadIdx.x;
    int s0 = slot_of[t * 2], s1 = slot_of[t * 2 + 1];
    float w0 = topw[t * 2], w1 = topw[t * 2 + 1];
    float4 a = ((const float4*)(x2 + (size_t)t * Dc))[c];
    float4 h0 = ((const float4*)(h2 + (size_t)s0 * Dc))[c];
    float4 h1 = ((const float4*)(h2 + (size_t)s1 * Dc))[c];
    float4 o;
    o.x = a.x + w0 * h0.x + w1 * h1.x;
    o.y = a.y + w0 * h0.y + w1 * h1.y;
    o.z = a.z + w0 * h0.z + w1 * h1.z;
    o.w = a.w + w0 * h0.w + w1 * h1.w;
    ((float4*)(out + (size_t)t * Dc))[c] = o;
}

// ---------------------------------------------------------------------------
// Workspace (MB):
//  [0,16) x2 fp32   [16,24) x2b    [24,32) hb
//  [32,38) wqkvT    [38,40) woT
//  [40,48) qb  [48,56) kb  [56,64) vt  [64,72) vb->aob
//  [72,136) w1T     [136,200) w2T  [200,264) h1  [264,296) h2
//  [296..) router scratch
// ---------------------------------------------------------------------------
extern "C" void kernel_launch(void* const* d_in, const int* in_sizes, int n_in,
                              void* d_out, int out_size, void* d_ws, size_t ws_size,
                              hipStream_t stream) {
    const float* x    = (const float*)d_in[0];
    const float* ln_g = (const float*)d_in[1];
    const float* ln_b = (const float*)d_in[2];
    const float* Wq   = (const float*)d_in[3];
    const float* Wk   = (const float*)d_in[4];
    const float* Wv   = (const float*)d_in[5];
    const float* Wo   = (const float*)d_in[6];
    const float* Wg   = (const float*)d_in[7];
    const float* W1   = (const float*)d_in[8];
    const float* b1   = (const float*)d_in[9];
    const float* W2   = (const float*)d_in[10];
    const float* b2   = (const float*)d_in[11];
    float* out = (float*)d_out;

    char* ws = (char*)d_ws;
    const size_t MB = 1ull << 20;
    float* x2    = (float*)(ws + 0 * MB);
    u16* x2b     = (u16*)(ws + 16 * MB);
    u16* hb      = (u16*)(ws + 24 * MB);
    u16* wqkvT   = (u16*)(ws + 32 * MB);
    u16* woT     = (u16*)(ws + 38 * MB);
    u16* qb      = (u16*)(ws + 40 * MB);
    u16* kb      = (u16*)(ws + 48 * MB);
    u16* vt      = (u16*)(ws + 56 * MB);
    u16* vb      = (u16*)(ws + 64 * MB);  // dead after btrans; reused as aob
    u16* aob     = (u16*)(ws + 64 * MB);
    u16* w1T     = (u16*)(ws + 72 * MB);
    u16* w2T     = (u16*)(ws + 136 * MB);
    u16* h1      = (u16*)(ws + 200 * MB);
    float* h2    = (float*)(ws + 264 * MB);
    char* sm     = ws + 296 * MB;
    float* topw    = (float*)(sm);
    int*   topi    = (int*)(sm + (1 << 15));
    int*   slot_of = (int*)(sm + 2 * (1 << 15));
    int*   list_tok= (int*)(sm + 3 * (1 << 15));
    int*   counts  = (int*)(sm + 4 * (1 << 15));
    int*   offsets = counts + 64;
    int*   cursor  = counts + 128;

    // weight transpose-casts
    tcast_kernel<<<dim3(16, 16, 1), 256, 0, stream>>>(Wq, wqkvT + 0 * 1024 * 1024, 1024, 1024, 0, 0);
    tcast_kernel<<<dim3(16, 16, 1), 256, 0, stream>>>(Wk, wqkvT + 1 * 1024 * 1024, 1024, 1024, 0, 0);
    tcast_kernel<<<dim3(16, 16, 1), 256, 0, stream>>>(Wv, wqkvT + 2 * 1024 * 1024, 1024, 1024, 0, 0);
    tcast_kernel<<<dim3(16, 16, 1), 256, 0, stream>>>(Wo, woT, 1024, 1024, 0, 0);
    tcast_kernel<<<dim3(64, 16, 8), 256, 0, stream>>>(W1, w1T, 1024, 4096,
                                                      (size_t)1024 * 4096, (size_t)4096 * 1024);
    tcast_kernel<<<dim3(16, 64, 8), 256, 0, stream>>>(W2, w2T, 4096, 1024,
                                                      (size_t)4096 * 1024, (size_t)1024 * 4096);

    // attention
    ln_kernel<<<NTOK, 256, 0, stream>>>(x, ln_g, ln_b, hb);
    gemm_mfma<0><<<dim3(24, 32), 256, 0, stream>>>(hb, wqkvT, 3072, 1024,
                                                   qb, kb, vb, nullptr, nullptr, nullptr, nullptr,
                                                   nullptr, nullptr, nullptr);
    btrans_kernel<<<dim3(16, 64), 256, 0, stream>>>(vb, vt, 4096, 1024);
    attn_mfma<<<dim3(Sc / 64, 16, 2), 256, 0, stream>>>(qb, kb, vt, aob);
    gemm_mfma<1><<<dim3(8, 32), 256, 0, stream>>>(aob, woT, 1024, 1024,
                                                  nullptr, nullptr, nullptr, x, x2, x2b, nullptr,
                                                  nullptr, nullptr, nullptr);

    // routing
    zero_small<<<1, 64, 0, stream>>>(counts, cursor);
    router_kernel<<<NTOK, 256, 0, stream>>>(x2, Wg, topi, topw, counts);
    scan_kernel<<<1, 1, 0, stream>>>(counts, offsets);
    scatter_kernel<<<NTOK / 256, 256, 0, stream>>>(topi, offsets, cursor, list_tok, slot_of);

    // experts
    gemm_mfma<2><<<dim3(32, 32, 8), 256, 0, stream>>>(x2b, w1T, 4096, 1024,
                                                      nullptr, nullptr, nullptr, nullptr, nullptr,
                                                      h1, b1, counts, offsets, list_tok);
    gemm_mfma<3><<<dim3(8, 32, 8), 256, 0, stream>>>(h1, w2T, 1024, 4096,
                                                     nullptr, nullptr, nullptr, nullptr, h2,
                                                     nullptr, b2, counts, offsets, list_tok);
    combine_kernel<<<NTOK, 256, 0, stream>>>(x2, h2, slot_of, topw, out);
}